// Round 3
// baseline (1191.463 us; speedup 1.0000x reference)
//
#include <hip/hip_runtime.h>
#include <hip/hip_bf16.h>

// ---------------- problem constants ----------------
constexpr int NN = 100000;   // nodes
constexpr int NE = 1600000;  // directed edges
constexpr int NH = 128;      // hidden width (== n_feat)
constexpr int NC = 64;       // classes
constexpr int NB = (NN + 127) / 128;   // 782 CSR-fill buckets (128 nodes each)

// ---------------- workspace layout (bytes) ----------------
constexpr size_t OFF_CNT   = 0;                         // N ints   (counts / chunk-scan in place)
constexpr size_t OFF_RP    = OFF_CNT  + 400384;         // N+1 ints (row_ptr)
constexpr size_t OFF_CUR   = OFF_RP   + 400384;         // N ints   (cursor)
constexpr size_t OFF_BSUM  = OFF_CUR  + 400384;         // 128 ints (block sums for scan)
constexpr size_t OFF_BCUR  = OFF_BSUM + 512;            // NB ints  (bucket cursors)
constexpr size_t OFF_DINV  = OFF_BCUR + 4096;           // N floats
constexpr size_t OFF_COL   = OFF_DINV + 400384;         // E ints
constexpr size_t OFF_H     = OFF_COL  + 6400000;        // N*128 floats (prescaled; also aliased as ebuf during preproc)
constexpr size_t OFF_X     = OFF_H    + 51200000;       // N*128 floats
// total ~110.4 MB;  ebuf (E int2 = 12.8 MB) aliases OFF_H (dead until first GEMM)

// ---------------- preprocessing kernels ----------------

__global__ __launch_bounds__(256) void count_kernel(const int* __restrict__ dst,
                                                    int* __restrict__ cnt) {
    int e = blockIdx.x * 256 + threadIdx.x;
    if (e < NE) atomicAdd(&cnt[dst[e]], 1);
}

__global__ __launch_bounds__(256) void dinv_kernel(const int* __restrict__ cnt,
                                                   float* __restrict__ dinv) {
    int i = blockIdx.x * 256 + threadIdx.x;
    if (i < NN) dinv[i] = rsqrtf((float)(cnt[i] + 1));   // +1 self loop
}

// exclusive scan, 3 phases, chunk = 1024 (256 thr x 4)
__global__ __launch_bounds__(256) void scan1_kernel(int* __restrict__ data,
                                                    int* __restrict__ bsum) {
    __shared__ int s[256];
    const int t = threadIdx.x;
    const int base = blockIdx.x * 1024;
    int v[4];
    #pragma unroll
    for (int j = 0; j < 4; ++j) {
        int idx = base + t * 4 + j;
        v[j] = (idx < NN) ? data[idx] : 0;
    }
    int tsum = v[0] + v[1] + v[2] + v[3];
    s[t] = tsum;
    __syncthreads();
    for (int off = 1; off < 256; off <<= 1) {
        int add = (t >= off) ? s[t - off] : 0;
        __syncthreads();
        s[t] += add;
        __syncthreads();
    }
    int run = s[t] - tsum;   // exclusive prefix for this thread within chunk
    #pragma unroll
    for (int j = 0; j < 4; ++j) {
        int idx = base + t * 4 + j;
        if (idx < NN) data[idx] = run;
        run += v[j];
    }
    if (t == 255) bsum[blockIdx.x] = s[255];
}

__global__ __launch_bounds__(128) void scan2_kernel(int* __restrict__ bsum, int nb) {
    __shared__ int s[128];
    const int t = threadIdx.x;
    int v = (t < nb) ? bsum[t] : 0;
    s[t] = v;
    __syncthreads();
    for (int off = 1; off < 128; off <<= 1) {
        int add = (t >= off) ? s[t - off] : 0;
        __syncthreads();
        s[t] += add;
        __syncthreads();
    }
    if (t < nb) bsum[t] = s[t] - v;  // exclusive
}

__global__ __launch_bounds__(256) void scan3_kernel(const int* __restrict__ chunkExcl,
                                                    const int* __restrict__ boff,
                                                    int* __restrict__ row_ptr,
                                                    int* __restrict__ cursor) {
    int i = blockIdx.x * 256 + threadIdx.x;
    if (i < NN) {
        int v = chunkExcl[i] + boff[i >> 10];
        row_ptr[i] = v;
        cursor[i]  = v;
    }
    if (i == 0) row_ptr[NN] = NE;
}

__global__ __launch_bounds__(256) void bcur_init_kernel(const int* __restrict__ rp,
                                                        int* __restrict__ bcur) {
    int b = blockIdx.x * 256 + threadIdx.x;
    if (b < NB) bcur[b] = rp[b * 128];
}

// phase C: append (src,dst) into bucket-ordered edge buffer.
// 782 active 8B-append regions -> write lines fill completely before eviction (~1x amplification).
__global__ __launch_bounds__(256) void scatter_kernel(const int* __restrict__ src,
                                                      const int* __restrict__ dst,
                                                      int* __restrict__ bcur,
                                                      int2* __restrict__ ebuf) {
    int e = blockIdx.x * 256 + threadIdx.x;
    if (e >= NE) return;
    int s = src[e], d = dst[e];
    int pos = atomicAdd(&bcur[d >> 7], 1);
    ebuf[pos] = make_int2(s, d);
}

// phase D: per-bucket CSR fill. All col writes land in the bucket's contiguous ~8KB slice,
// all cursor atomics in a 512B slice -> L2-hot.
__global__ __launch_bounds__(256) void csrfill_kernel(const int2* __restrict__ ebuf,
                                                      const int* __restrict__ rp,
                                                      int* __restrict__ cur,
                                                      int* __restrict__ col) {
    int b = blockIdx.x;
    int beg = rp[b * 128];
    int hi  = (b + 1) * 128; if (hi > NN) hi = NN;
    int end = rp[hi];
    for (int e = beg + threadIdx.x; e < end; e += 256) {
        int2 sd = ebuf[e];
        int pos = atomicAdd(&cur[sd.y], 1);
        col[pos] = sd.x;
    }
}

// ---------------- GEMM:  H[n][h*64 + 64 cols] = X[n][:] @ W, optionally row-prescaled by dinv ----
__global__ __launch_bounds__(256) void gemm_kernel(const float* __restrict__ X,
                                                   const float* __restrict__ W0,
                                                   const float* __restrict__ W1,
                                                   int wstride,
                                                   const float* __restrict__ dinv,
                                                   int scaleMask,
                                                   float* __restrict__ H) {
    __shared__ float sW[128][64];
    __shared__ float sX[64][132];   // padded: 132 % 32 == 4 -> 2-way (free) on reads

    const int t = threadIdx.x;
    const int h = blockIdx.y;
    const float* __restrict__ W = h ? W1 : W0;
    const bool doScale = (scaleMask >> h) & 1;

    // load W slice: 128 x 64
    #pragma unroll
    for (int i = 0; i < 8; ++i) {
        int e = t * 4 + i * 1024;
        int k = e >> 6, c = e & 63;
        float4 w = *(const float4*)&W[(size_t)k * wstride + c];
        *(float4*)&sW[k][c] = w;
    }
    // load X tile: 64 nodes x 128
    const int tileBase = blockIdx.x * 64;
    #pragma unroll
    for (int i = 0; i < 8; ++i) {
        int e = t * 4 + i * 1024;
        int node = e >> 7, k = e & 127;
        int gn = tileBase + node;
        float4 v = make_float4(0.f, 0.f, 0.f, 0.f);
        if (gn < NN) v = *(const float4*)&X[(size_t)gn * 128 + k];
        *(float4*)&sX[node][k] = v;
    }
    __syncthreads();

    const int tx = t & 15;    // out group: cols tx*4 .. tx*4+3
    const int ty = t >> 4;    // node group: nodes ty*4 .. ty*4+3

    float acc[4][4];
    #pragma unroll
    for (int r = 0; r < 4; ++r)
        #pragma unroll
        for (int c = 0; c < 4; ++c) acc[r][c] = 0.f;

    #pragma unroll 4
    for (int k = 0; k < 128; k += 4) {
        float4 xr[4], wr[4];
        #pragma unroll
        for (int r = 0; r < 4; ++r) xr[r] = *(const float4*)&sX[ty * 4 + r][k];
        #pragma unroll
        for (int j = 0; j < 4; ++j) wr[j] = *(const float4*)&sW[k + j][tx * 4];
        #pragma unroll
        for (int r = 0; r < 4; ++r) {
            #pragma unroll
            for (int j = 0; j < 4; ++j) {
                float xv = (j == 0) ? xr[r].x : (j == 1) ? xr[r].y : (j == 2) ? xr[r].z : xr[r].w;
                acc[r][0] += xv * wr[j].x;
                acc[r][1] += xv * wr[j].y;
                acc[r][2] += xv * wr[j].z;
                acc[r][3] += xv * wr[j].w;
            }
        }
    }

    #pragma unroll
    for (int r = 0; r < 4; ++r) {
        int gn = tileBase + ty * 4 + r;
        if (gn < NN) {
            float s = doScale ? dinv[gn] : 1.f;
            float4 o = make_float4(acc[r][0] * s, acc[r][1] * s, acc[r][2] * s, acc[r][3] * s);
            *(float4*)&H[(size_t)gn * 128 + h * 64 + tx * 4] = o;
        }
    }
}

// ---------------- aggregation: 128-feature layers (conv + bias + residual + relu) ----------------
// Hs rows are prescaled by dinv[row]; out = relu(dinv[i]*(Hs[i] + sum_e Hs[col[e]]) + bias + Xold)
__global__ __launch_bounds__(256) void agg128_kernel(const float* __restrict__ Hs,
                                                     const float* __restrict__ Xold,
                                                     const int* __restrict__ rp,
                                                     const int* __restrict__ col,
                                                     const float* __restrict__ dinv,
                                                     const float* __restrict__ bias,
                                                     float* __restrict__ Xnew) {
    const int wid  = threadIdx.x >> 6;
    const int lane = threadIdx.x & 63;
    const int i = blockIdx.x * 4 + wid;
    if (i >= NN) return;

    const float2* __restrict__ H2 = (const float2*)Hs;

    const float di = dinv[i];
    const float2 b2 = ((const float2*)bias)[lane];
    const float2 xo = ((const float2*)Xold)[(size_t)i * 64 + lane];

    float2 hv = H2[(size_t)i * 64 + lane];   // self term
    float ax = hv.x, ay = hv.y;

    const int beg = rp[i], end = rp[i + 1];
    int e = beg;
    // 8x unrolled gather: 8 independent 512B row reads in flight per wave
    for (; e + 8 <= end; e += 8) {
        int s0 = col[e],     s1 = col[e + 1], s2 = col[e + 2], s3 = col[e + 3];
        int s4 = col[e + 4], s5 = col[e + 5], s6 = col[e + 6], s7 = col[e + 7];
        float2 m0 = H2[(size_t)s0 * 64 + lane];
        float2 m1 = H2[(size_t)s1 * 64 + lane];
        float2 m2 = H2[(size_t)s2 * 64 + lane];
        float2 m3 = H2[(size_t)s3 * 64 + lane];
        float2 m4 = H2[(size_t)s4 * 64 + lane];
        float2 m5 = H2[(size_t)s5 * 64 + lane];
        float2 m6 = H2[(size_t)s6 * 64 + lane];
        float2 m7 = H2[(size_t)s7 * 64 + lane];
        ax += ((m0.x + m1.x) + (m2.x + m3.x)) + ((m4.x + m5.x) + (m6.x + m7.x));
        ay += ((m0.y + m1.y) + (m2.y + m3.y)) + ((m4.y + m5.y) + (m6.y + m7.y));
    }
    for (; e + 4 <= end; e += 4) {
        int s0 = col[e], s1 = col[e + 1], s2 = col[e + 2], s3 = col[e + 3];
        float2 m0 = H2[(size_t)s0 * 64 + lane];
        float2 m1 = H2[(size_t)s1 * 64 + lane];
        float2 m2 = H2[(size_t)s2 * 64 + lane];
        float2 m3 = H2[(size_t)s3 * 64 + lane];
        ax += (m0.x + m1.x) + (m2.x + m3.x);
        ay += (m0.y + m1.y) + (m2.y + m3.y);
    }
    for (; e < end; ++e) {
        float2 m = H2[(size_t)col[e] * 64 + lane];
        ax += m.x;
        ay += m.y;
    }

    float ox = fmaxf(di * ax + b2.x + xo.x, 0.f);
    float oy = fmaxf(di * ay + b2.y + xo.y, 0.f);
    ((float2*)Xnew)[(size_t)i * 64 + lane] = make_float2(ox, oy);
}

// ---------------- final layer: 64-feature conv + bias + skip ----------------
// H rows: cols 0..63 = x@W_out (prescaled by dinv), cols 64..127 = x@W_skip_out (raw)
__global__ __launch_bounds__(256) void aggout_kernel(const float* __restrict__ Hs,
                                                     const int* __restrict__ rp,
                                                     const int* __restrict__ col,
                                                     const float* __restrict__ dinv,
                                                     const float* __restrict__ bias,
                                                     float* __restrict__ out) {
    const int wid  = threadIdx.x >> 6;
    const int lane = threadIdx.x & 63;
    const int i = blockIdx.x * 4 + wid;
    if (i >= NN) return;

    const float di = dinv[i];
    const float b  = bias[lane];
    const float sk = Hs[(size_t)i * 128 + 64 + lane];   // skip projection (unscaled)

    float a = Hs[(size_t)i * 128 + lane];               // self term
    const int beg = rp[i], end = rp[i + 1];
    int e = beg;
    for (; e + 8 <= end; e += 8) {
        int s0 = col[e],     s1 = col[e + 1], s2 = col[e + 2], s3 = col[e + 3];
        int s4 = col[e + 4], s5 = col[e + 5], s6 = col[e + 6], s7 = col[e + 7];
        float m0 = Hs[(size_t)s0 * 128 + lane];
        float m1 = Hs[(size_t)s1 * 128 + lane];
        float m2 = Hs[(size_t)s2 * 128 + lane];
        float m3 = Hs[(size_t)s3 * 128 + lane];
        float m4 = Hs[(size_t)s4 * 128 + lane];
        float m5 = Hs[(size_t)s5 * 128 + lane];
        float m6 = Hs[(size_t)s6 * 128 + lane];
        float m7 = Hs[(size_t)s7 * 128 + lane];
        a += ((m0 + m1) + (m2 + m3)) + ((m4 + m5) + (m6 + m7));
    }
    for (; e + 4 <= end; e += 4) {
        int s0 = col[e], s1 = col[e + 1], s2 = col[e + 2], s3 = col[e + 3];
        float m0 = Hs[(size_t)s0 * 128 + lane];
        float m1 = Hs[(size_t)s1 * 128 + lane];
        float m2 = Hs[(size_t)s2 * 128 + lane];
        float m3 = Hs[(size_t)s3 * 128 + lane];
        a += (m0 + m1) + (m2 + m3);
    }
    for (; e < end; ++e) a += Hs[(size_t)col[e] * 128 + lane];

    out[(size_t)i * 64 + lane] = di * a + b + sk;
}

// ---------------- launch ----------------
extern "C" void kernel_launch(void* const* d_in, const int* in_sizes, int n_in,
                              void* d_out, int out_size, void* d_ws, size_t ws_size,
                              hipStream_t stream) {
    const float* x      = (const float*)d_in[0];
    const int*   ei     = (const int*)d_in[1];
    const float* W_in   = (const float*)d_in[2];
    const float* b_in   = (const float*)d_in[3];
    const float* W_mid0 = (const float*)d_in[4];
    const float* b_mid0 = (const float*)d_in[5];
    const float* W_mid1 = (const float*)d_in[6];
    const float* b_mid1 = (const float*)d_in[7];
    const float* W_out  = (const float*)d_in[8];
    const float* b_out  = (const float*)d_in[9];
    const float* W_skip = (const float*)d_in[10];

    const int* esrc = ei;        // edge_index[0]
    const int* edst = ei + NE;   // edge_index[1]

    char* ws = (char*)d_ws;
    int*   cnt    = (int*)  (ws + OFF_CNT);
    int*   rp     = (int*)  (ws + OFF_RP);
    int*   cur    = (int*)  (ws + OFF_CUR);
    int*   bsum   = (int*)  (ws + OFF_BSUM);
    int*   bcur   = (int*)  (ws + OFF_BCUR);
    float* dinv   = (float*)(ws + OFF_DINV);
    int*   col    = (int*)  (ws + OFF_COL);
    float* hbuf   = (float*)(ws + OFF_H);
    int2*  ebuf   = (int2*) (ws + OFF_H);    // alias: dead before first GEMM
    float* xbuf   = (float*)(ws + OFF_X);
    float* outp   = (float*)d_out;

    const int nbScan = (NN + 1023) / 1024;           // 98
    const dim3 gemmGrid((NN + 63) / 64, 2);          // 1563 x 2
    const int aggGrid = (NN + 3) / 4;                // 25000
    const int eGrid   = (NE + 255) / 256;            // 6250
    const int nGrid   = (NN + 255) / 256;            // 391
    const int bGrid   = (NB + 255) / 256;            // 4

    // ---- graph preprocessing (every call: ws is not re-initialized by harness) ----
    hipMemsetAsync(cnt, 0, (size_t)NN * 4, stream);
    count_kernel<<<eGrid, 256, 0, stream>>>(edst, cnt);
    dinv_kernel<<<nGrid, 256, 0, stream>>>(cnt, dinv);
    scan1_kernel<<<nbScan, 256, 0, stream>>>(cnt, bsum);
    scan2_kernel<<<1, 128, 0, stream>>>(bsum, nbScan);
    scan3_kernel<<<nGrid, 256, 0, stream>>>(cnt, bsum, rp, cur);
    bcur_init_kernel<<<bGrid, 256, 0, stream>>>(rp, bcur);
    scatter_kernel<<<eGrid, 256, 0, stream>>>(esrc, edst, bcur, ebuf);
    csrfill_kernel<<<NB, 256, 0, stream>>>(ebuf, rp, cur, col);

    // ---- layer 1 (reads input x, writes xbuf) ----
    gemm_kernel<<<gemmGrid, 256, 0, stream>>>(x, W_in, W_in + 64, 128, dinv, 3, hbuf);
    agg128_kernel<<<aggGrid, 256, 0, stream>>>(hbuf, x, rp, col, dinv, b_in, xbuf);

    // ---- layer 2 ----
    gemm_kernel<<<gemmGrid, 256, 0, stream>>>(xbuf, W_mid0, W_mid0 + 64, 128, dinv, 3, hbuf);
    agg128_kernel<<<aggGrid, 256, 0, stream>>>(hbuf, xbuf, rp, col, dinv, b_mid0, xbuf);

    // ---- layer 3 ----
    gemm_kernel<<<gemmGrid, 256, 0, stream>>>(xbuf, W_mid1, W_mid1 + 64, 128, dinv, 3, hbuf);
    agg128_kernel<<<aggGrid, 256, 0, stream>>>(hbuf, xbuf, rp, col, dinv, b_mid1, xbuf);

    // ---- layer 4: fused [W_out | W_skip_out] GEMM (scale only W_out half), then conv+bias+skip ----
    gemm_kernel<<<gemmGrid, 256, 0, stream>>>(xbuf, W_out, W_skip, 64, dinv, 1, hbuf);
    aggout_kernel<<<aggGrid, 256, 0, stream>>>(hbuf, rp, col, dinv, b_out, outp);
}

// Round 4
// 743.216 us; speedup vs baseline: 1.6031x; 1.6031x over previous
//
#include <hip/hip_runtime.h>
#include <hip/hip_bf16.h>

// ---------------- problem constants ----------------
constexpr int NN = 100000;   // nodes
constexpr int NE = 1600000;  // directed edges
constexpr int NH = 128;      // hidden width (== n_feat)
constexpr int NC = 64;       // classes
constexpr int BKN  = 256;                  // nodes per bucket
constexpr int NB2  = (NN + BKN - 1) / BKN; // 391 buckets
constexpr int TILE = 4096;                 // edges per scatter block
constexpr int NT   = (NE + TILE - 1) / TILE; // 391 tiles

// ---------------- workspace layout (bytes) ----------------
constexpr size_t OFF_BCNT  = 0;                         // NB2+1 ints (bucket counts)
constexpr size_t OFF_BBASE = OFF_BCNT  + 2048;          // NB2+1 ints (bucket bases)
constexpr size_t OFF_BCUR  = OFF_BBASE + 2048;          // NB2 ints   (bucket cursors)
constexpr size_t OFF_RP    = OFF_BCUR  + 2048;          // NN+1 ints  (row_ptr)
constexpr size_t OFF_DINV  = OFF_RP    + 400384;        // NN floats
constexpr size_t OFF_COL   = OFF_DINV  + 400384;        // E ints
constexpr size_t OFF_H     = OFF_COL   + 6400000;       // N*128 floats (prescaled; aliased as ebuf during preproc)
constexpr size_t OFF_X     = OFF_H     + 51200000;      // N*128 floats
// total ~110 MB;  ebuf (E int2 = 12.8 MB) aliases OFF_H (dead until first GEMM)

// ---------------- preprocessing: radix-partition CSR build ----------------

// per-tile LDS histogram of buckets -> one global atomicAdd per (block,bucket)
__global__ __launch_bounds__(256) void bhist_kernel(const int* __restrict__ edst,
                                                    int* __restrict__ bcnt) {
    __shared__ int h[NB2];
    for (int i = threadIdx.x; i < NB2; i += 256) h[i] = 0;
    __syncthreads();
    const int base = blockIdx.x * TILE;
    #pragma unroll
    for (int j = 0; j < 16; ++j) {
        int e = base + j * 256 + threadIdx.x;
        if (e < NE) atomicAdd(&h[edst[e] >> 8], 1);
    }
    __syncthreads();
    for (int i = threadIdx.x; i < NB2; i += 256)
        if (h[i]) atomicAdd(&bcnt[i], h[i]);
}

// single-block exclusive scan of bucket counts
__global__ __launch_bounds__(512) void bscan_kernel(const int* __restrict__ bcnt,
                                                    int* __restrict__ bbase,
                                                    int* __restrict__ bcur) {
    __shared__ int s[512];
    const int t = threadIdx.x;
    int v = (t < NB2) ? bcnt[t] : 0;
    s[t] = v;
    __syncthreads();
    for (int off = 1; off < 512; off <<= 1) {
        int a = (t >= off) ? s[t - off] : 0;
        __syncthreads();
        s[t] += a;
        __syncthreads();
    }
    int excl = s[t] - v;
    if (t < NB2) { bbase[t] = excl; bcur[t] = excl; }
    if (t == NB2 - 1) bbase[NB2] = excl + v;   // == NE
}

// partition edges into bucket-ordered ebuf.  One global atomic per (block,bucket);
// per-edge ranking via LDS cursors; each bucket-run written by one block -> full lines.
__global__ __launch_bounds__(256) void scatter2_kernel(const int* __restrict__ esrc,
                                                       const int* __restrict__ edst,
                                                       int* __restrict__ bcur,
                                                       int2* __restrict__ ebuf) {
    __shared__ int h[NB2];
    __shared__ int cur[NB2];
    for (int i = threadIdx.x; i < NB2; i += 256) h[i] = 0;
    __syncthreads();
    const int base = blockIdx.x * TILE;
    #pragma unroll
    for (int j = 0; j < 16; ++j) {
        int e = base + j * 256 + threadIdx.x;
        if (e < NE) atomicAdd(&h[edst[e] >> 8], 1);
    }
    __syncthreads();
    for (int i = threadIdx.x; i < NB2; i += 256) {
        int c = h[i];
        cur[i] = c ? atomicAdd(&bcur[i], c) : 0;
    }
    __syncthreads();
    #pragma unroll
    for (int j = 0; j < 16; ++j) {
        int e = base + j * 256 + threadIdx.x;
        if (e < NE) {
            int s = esrc[e], d = edst[e];
            int pos = atomicAdd(&cur[d >> 8], 1);
            ebuf[pos] = make_int2(s, d);
        }
    }
}

// one block per bucket: LDS-local node counts + scan -> rp, dinv, col. All atomics in LDS;
// col writes confined to this block's contiguous ~16KB slice.
__global__ __launch_bounds__(256) void csrfill2_kernel(const int2* __restrict__ ebuf,
                                                       const int* __restrict__ bbase,
                                                       int* __restrict__ rp,
                                                       float* __restrict__ dinv,
                                                       int* __restrict__ col) {
    __shared__ int cnt[256];
    __shared__ int cursor[256];
    __shared__ int s[256];
    __shared__ int sbeg, send;
    const int b = blockIdx.x;
    const int t = threadIdx.x;
    if (t == 0) { sbeg = bbase[b]; send = bbase[b + 1]; }
    cnt[t] = 0;
    __syncthreads();
    const int beg = sbeg, end = send;
    const int node0 = b * BKN;

    for (int e = beg + t; e < end; e += 256)
        atomicAdd(&cnt[ebuf[e].y & 255], 1);
    __syncthreads();

    int v = cnt[t];
    s[t] = v;
    __syncthreads();
    for (int off = 1; off < 256; off <<= 1) {
        int a = (t >= off) ? s[t - off] : 0;
        __syncthreads();
        s[t] += a;
        __syncthreads();
    }
    int excl = s[t] - v;
    int gnode = node0 + t;
    if (gnode < NN) {
        rp[gnode]   = beg + excl;
        dinv[gnode] = rsqrtf((float)(v + 1));   // +1 self loop
    }
    cursor[t] = beg + excl;
    if (b == NB2 - 1 && t == 0) rp[NN] = NE;
    __syncthreads();

    for (int e = beg + t; e < end; e += 256) {
        int2 sd = ebuf[e];
        int pos = atomicAdd(&cursor[sd.y & 255], 1);
        col[pos] = sd.x;
    }
}

// ---------------- GEMM:  H[n][h*64 + 64 cols] = X[n][:] @ W, optionally row-prescaled by dinv ----
__global__ __launch_bounds__(256) void gemm_kernel(const float* __restrict__ X,
                                                   const float* __restrict__ W0,
                                                   const float* __restrict__ W1,
                                                   int wstride,
                                                   const float* __restrict__ dinv,
                                                   int scaleMask,
                                                   float* __restrict__ H) {
    __shared__ float sW[128][64];
    __shared__ float sX[64][132];   // padded: 132 % 32 == 4 -> 2-way (free) on reads

    const int t = threadIdx.x;
    const int h = blockIdx.y;
    const float* __restrict__ W = h ? W1 : W0;
    const bool doScale = (scaleMask >> h) & 1;

    // load W slice: 128 x 64
    #pragma unroll
    for (int i = 0; i < 8; ++i) {
        int e = t * 4 + i * 1024;
        int k = e >> 6, c = e & 63;
        float4 w = *(const float4*)&W[(size_t)k * wstride + c];
        *(float4*)&sW[k][c] = w;
    }
    // load X tile: 64 nodes x 128
    const int tileBase = blockIdx.x * 64;
    #pragma unroll
    for (int i = 0; i < 8; ++i) {
        int e = t * 4 + i * 1024;
        int node = e >> 7, k = e & 127;
        int gn = tileBase + node;
        float4 v = make_float4(0.f, 0.f, 0.f, 0.f);
        if (gn < NN) v = *(const float4*)&X[(size_t)gn * 128 + k];
        *(float4*)&sX[node][k] = v;
    }
    __syncthreads();

    const int tx = t & 15;    // out group: cols tx*4 .. tx*4+3
    const int ty = t >> 4;    // node group: nodes ty*4 .. ty*4+3

    float acc[4][4];
    #pragma unroll
    for (int r = 0; r < 4; ++r)
        #pragma unroll
        for (int c = 0; c < 4; ++c) acc[r][c] = 0.f;

    #pragma unroll 4
    for (int k = 0; k < 128; k += 4) {
        float4 xr[4], wr[4];
        #pragma unroll
        for (int r = 0; r < 4; ++r) xr[r] = *(const float4*)&sX[ty * 4 + r][k];
        #pragma unroll
        for (int j = 0; j < 4; ++j) wr[j] = *(const float4*)&sW[k + j][tx * 4];
        #pragma unroll
        for (int r = 0; r < 4; ++r) {
            #pragma unroll
            for (int j = 0; j < 4; ++j) {
                float xv = (j == 0) ? xr[r].x : (j == 1) ? xr[r].y : (j == 2) ? xr[r].z : xr[r].w;
                acc[r][0] += xv * wr[j].x;
                acc[r][1] += xv * wr[j].y;
                acc[r][2] += xv * wr[j].z;
                acc[r][3] += xv * wr[j].w;
            }
        }
    }

    #pragma unroll
    for (int r = 0; r < 4; ++r) {
        int gn = tileBase + ty * 4 + r;
        if (gn < NN) {
            float s = doScale ? dinv[gn] : 1.f;
            float4 o = make_float4(acc[r][0] * s, acc[r][1] * s, acc[r][2] * s, acc[r][3] * s);
            *(float4*)&H[(size_t)gn * 128 + h * 64 + tx * 4] = o;
        }
    }
}

// ---------------- aggregation: 128-feature layers (conv + bias + residual + relu) ----------------
// Hs rows are prescaled by dinv[row]; out = relu(dinv[i]*(Hs[i] + sum_e Hs[col[e]]) + bias + Xold)
__global__ __launch_bounds__(256) void agg128_kernel(const float* __restrict__ Hs,
                                                     const float* __restrict__ Xold,
                                                     const int* __restrict__ rp,
                                                     const int* __restrict__ col,
                                                     const float* __restrict__ dinv,
                                                     const float* __restrict__ bias,
                                                     float* __restrict__ Xnew) {
    const int wid  = threadIdx.x >> 6;
    const int lane = threadIdx.x & 63;
    const int i = blockIdx.x * 4 + wid;
    if (i >= NN) return;

    const float2* __restrict__ H2 = (const float2*)Hs;

    const float di = dinv[i];
    const float2 b2 = ((const float2*)bias)[lane];
    const float2 xo = ((const float2*)Xold)[(size_t)i * 64 + lane];

    float2 hv = H2[(size_t)i * 64 + lane];   // self term
    float ax = hv.x, ay = hv.y;

    const int beg = rp[i], end = rp[i + 1];
    int e = beg;
    for (; e + 8 <= end; e += 8) {
        int s0 = col[e],     s1 = col[e + 1], s2 = col[e + 2], s3 = col[e + 3];
        int s4 = col[e + 4], s5 = col[e + 5], s6 = col[e + 6], s7 = col[e + 7];
        float2 m0 = H2[(size_t)s0 * 64 + lane];
        float2 m1 = H2[(size_t)s1 * 64 + lane];
        float2 m2 = H2[(size_t)s2 * 64 + lane];
        float2 m3 = H2[(size_t)s3 * 64 + lane];
        float2 m4 = H2[(size_t)s4 * 64 + lane];
        float2 m5 = H2[(size_t)s5 * 64 + lane];
        float2 m6 = H2[(size_t)s6 * 64 + lane];
        float2 m7 = H2[(size_t)s7 * 64 + lane];
        ax += ((m0.x + m1.x) + (m2.x + m3.x)) + ((m4.x + m5.x) + (m6.x + m7.x));
        ay += ((m0.y + m1.y) + (m2.y + m3.y)) + ((m4.y + m5.y) + (m6.y + m7.y));
    }
    for (; e + 4 <= end; e += 4) {
        int s0 = col[e], s1 = col[e + 1], s2 = col[e + 2], s3 = col[e + 3];
        float2 m0 = H2[(size_t)s0 * 64 + lane];
        float2 m1 = H2[(size_t)s1 * 64 + lane];
        float2 m2 = H2[(size_t)s2 * 64 + lane];
        float2 m3 = H2[(size_t)s3 * 64 + lane];
        ax += (m0.x + m1.x) + (m2.x + m3.x);
        ay += (m0.y + m1.y) + (m2.y + m3.y);
    }
    for (; e < end; ++e) {
        float2 m = H2[(size_t)col[e] * 64 + lane];
        ax += m.x;
        ay += m.y;
    }

    float ox = fmaxf(di * ax + b2.x + xo.x, 0.f);
    float oy = fmaxf(di * ay + b2.y + xo.y, 0.f);
    ((float2*)Xnew)[(size_t)i * 64 + lane] = make_float2(ox, oy);
}

// ---------------- final layer: 64-feature conv + bias + skip ----------------
// H rows: cols 0..63 = x@W_out (prescaled by dinv), cols 64..127 = x@W_skip_out (raw)
__global__ __launch_bounds__(256) void aggout_kernel(const float* __restrict__ Hs,
                                                     const int* __restrict__ rp,
                                                     const int* __restrict__ col,
                                                     const float* __restrict__ dinv,
                                                     const float* __restrict__ bias,
                                                     float* __restrict__ out) {
    const int wid  = threadIdx.x >> 6;
    const int lane = threadIdx.x & 63;
    const int i = blockIdx.x * 4 + wid;
    if (i >= NN) return;

    const float di = dinv[i];
    const float b  = bias[lane];
    const float sk = Hs[(size_t)i * 128 + 64 + lane];   // skip projection (unscaled)

    float a = Hs[(size_t)i * 128 + lane];               // self term
    const int beg = rp[i], end = rp[i + 1];
    int e = beg;
    for (; e + 8 <= end; e += 8) {
        int s0 = col[e],     s1 = col[e + 1], s2 = col[e + 2], s3 = col[e + 3];
        int s4 = col[e + 4], s5 = col[e + 5], s6 = col[e + 6], s7 = col[e + 7];
        float m0 = Hs[(size_t)s0 * 128 + lane];
        float m1 = Hs[(size_t)s1 * 128 + lane];
        float m2 = Hs[(size_t)s2 * 128 + lane];
        float m3 = Hs[(size_t)s3 * 128 + lane];
        float m4 = Hs[(size_t)s4 * 128 + lane];
        float m5 = Hs[(size_t)s5 * 128 + lane];
        float m6 = Hs[(size_t)s6 * 128 + lane];
        float m7 = Hs[(size_t)s7 * 128 + lane];
        a += ((m0 + m1) + (m2 + m3)) + ((m4 + m5) + (m6 + m7));
    }
    for (; e + 4 <= end; e += 4) {
        int s0 = col[e], s1 = col[e + 1], s2 = col[e + 2], s3 = col[e + 3];
        float m0 = Hs[(size_t)s0 * 128 + lane];
        float m1 = Hs[(size_t)s1 * 128 + lane];
        float m2 = Hs[(size_t)s2 * 128 + lane];
        float m3 = Hs[(size_t)s3 * 128 + lane];
        a += (m0 + m1) + (m2 + m3);
    }
    for (; e < end; ++e) a += Hs[(size_t)col[e] * 128 + lane];

    out[(size_t)i * 64 + lane] = di * a + b + sk;
}

// ---------------- launch ----------------
extern "C" void kernel_launch(void* const* d_in, const int* in_sizes, int n_in,
                              void* d_out, int out_size, void* d_ws, size_t ws_size,
                              hipStream_t stream) {
    const float* x      = (const float*)d_in[0];
    const int*   ei     = (const int*)d_in[1];
    const float* W_in   = (const float*)d_in[2];
    const float* b_in   = (const float*)d_in[3];
    const float* W_mid0 = (const float*)d_in[4];
    const float* b_mid0 = (const float*)d_in[5];
    const float* W_mid1 = (const float*)d_in[6];
    const float* b_mid1 = (const float*)d_in[7];
    const float* W_out  = (const float*)d_in[8];
    const float* b_out  = (const float*)d_in[9];
    const float* W_skip = (const float*)d_in[10];

    const int* esrc = ei;        // edge_index[0]
    const int* edst = ei + NE;   // edge_index[1]

    char* ws = (char*)d_ws;
    int*   bcnt   = (int*)  (ws + OFF_BCNT);
    int*   bbase  = (int*)  (ws + OFF_BBASE);
    int*   bcur   = (int*)  (ws + OFF_BCUR);
    int*   rp     = (int*)  (ws + OFF_RP);
    float* dinv   = (float*)(ws + OFF_DINV);
    int*   col    = (int*)  (ws + OFF_COL);
    float* hbuf   = (float*)(ws + OFF_H);
    int2*  ebuf   = (int2*) (ws + OFF_H);    // alias: dead before first GEMM
    float* xbuf   = (float*)(ws + OFF_X);
    float* outp   = (float*)d_out;

    const dim3 gemmGrid((NN + 63) / 64, 2);          // 1563 x 2
    const int aggGrid = (NN + 3) / 4;                // 25000

    // ---- graph preprocessing (every call: ws is not re-initialized by harness) ----
    hipMemsetAsync(bcnt, 0, (size_t)(NB2 + 1) * 4, stream);
    bhist_kernel<<<NT, 256, 0, stream>>>(edst, bcnt);
    bscan_kernel<<<1, 512, 0, stream>>>(bcnt, bbase, bcur);
    scatter2_kernel<<<NT, 256, 0, stream>>>(esrc, edst, bcur, ebuf);
    csrfill2_kernel<<<NB2, 256, 0, stream>>>(ebuf, bbase, rp, dinv, col);

    // ---- layer 1 (reads input x, writes xbuf) ----
    gemm_kernel<<<gemmGrid, 256, 0, stream>>>(x, W_in, W_in + 64, 128, dinv, 3, hbuf);
    agg128_kernel<<<aggGrid, 256, 0, stream>>>(hbuf, x, rp, col, dinv, b_in, xbuf);

    // ---- layer 2 ----
    gemm_kernel<<<gemmGrid, 256, 0, stream>>>(xbuf, W_mid0, W_mid0 + 64, 128, dinv, 3, hbuf);
    agg128_kernel<<<aggGrid, 256, 0, stream>>>(hbuf, xbuf, rp, col, dinv, b_mid0, xbuf);

    // ---- layer 3 ----
    gemm_kernel<<<gemmGrid, 256, 0, stream>>>(xbuf, W_mid1, W_mid1 + 64, 128, dinv, 3, hbuf);
    agg128_kernel<<<aggGrid, 256, 0, stream>>>(hbuf, xbuf, rp, col, dinv, b_mid1, xbuf);

    // ---- layer 4: fused [W_out | W_skip_out] GEMM (scale only W_out half), then conv+bias+skip ----
    gemm_kernel<<<gemmGrid, 256, 0, stream>>>(xbuf, W_out, W_skip, 64, dinv, 1, hbuf);
    aggout_kernel<<<aggGrid, 256, 0, stream>>>(hbuf, rp, col, dinv, b_out, outp);
}

// Round 5
// 569.789 us; speedup vs baseline: 2.0911x; 1.3044x over previous
//
#include <hip/hip_runtime.h>
#include <hip/hip_bf16.h>

// ---------------- problem constants ----------------
constexpr int NN = 100000;   // nodes
constexpr int NE = 1600000;  // directed edges
constexpr int NH = 128;      // hidden width (== n_feat)
constexpr int NC = 64;       // classes
constexpr int BKN  = 256;                  // nodes per bucket
constexpr int NB2  = (NN + BKN - 1) / BKN; // 391 buckets
constexpr int TILE = 4096;                 // edges per scatter block
constexpr int NT   = (NE + TILE - 1) / TILE; // 391 tiles

// ---------------- bf16 helpers (RNE) ----------------
__device__ __forceinline__ unsigned short f2bf(float f) {
    unsigned int u = __float_as_uint(f);
    unsigned int r = (u + 0x7fffu + ((u >> 16) & 1u)) >> 16;
    return (unsigned short)r;
}
__device__ __forceinline__ float bflo(unsigned int u) { return __uint_as_float(u << 16); }
__device__ __forceinline__ float bfhi(unsigned int u) { return __uint_as_float(u & 0xffff0000u); }
__device__ __forceinline__ float bf2f(unsigned short h) { return __uint_as_float(((unsigned int)h) << 16); }

// ---------------- workspace layout (bytes) ----------------
constexpr size_t OFF_BCNT  = 0;                         // NB2+1 ints (bucket counts)
constexpr size_t OFF_BBASE = OFF_BCNT  + 2048;          // NB2+1 ints (bucket bases)
constexpr size_t OFF_BCUR  = OFF_BBASE + 2048;          // NB2 ints   (bucket cursors)
constexpr size_t OFF_RP    = OFF_BCUR  + 2048;          // NN+1 ints  (row_ptr)
constexpr size_t OFF_DINV  = OFF_RP    + 400384;        // NN floats
constexpr size_t OFF_COL   = OFF_DINV  + 400384;        // E ints
constexpr size_t OFF_H     = OFF_COL   + 6400000;       // N*128 bf16 (prescaled; aliased as ebuf during preproc)
constexpr size_t OFF_X     = OFF_H     + 25600000;      // N*128 floats
// ebuf (E int2 = 12.8 MB) aliases OFF_H (25.6 MB region; dead until first GEMM)

// ---------------- preprocessing: radix-partition CSR build ----------------

__global__ __launch_bounds__(256) void bhist_kernel(const int* __restrict__ edst,
                                                    int* __restrict__ bcnt) {
    __shared__ int h[NB2];
    for (int i = threadIdx.x; i < NB2; i += 256) h[i] = 0;
    __syncthreads();
    const int base = blockIdx.x * TILE;
    #pragma unroll
    for (int j = 0; j < 16; ++j) {
        int e = base + j * 256 + threadIdx.x;
        if (e < NE) atomicAdd(&h[edst[e] >> 8], 1);
    }
    __syncthreads();
    for (int i = threadIdx.x; i < NB2; i += 256)
        if (h[i]) atomicAdd(&bcnt[i], h[i]);
}

__global__ __launch_bounds__(512) void bscan_kernel(const int* __restrict__ bcnt,
                                                    int* __restrict__ bbase,
                                                    int* __restrict__ bcur) {
    __shared__ int s[512];
    const int t = threadIdx.x;
    int v = (t < NB2) ? bcnt[t] : 0;
    s[t] = v;
    __syncthreads();
    for (int off = 1; off < 512; off <<= 1) {
        int a = (t >= off) ? s[t - off] : 0;
        __syncthreads();
        s[t] += a;
        __syncthreads();
    }
    int excl = s[t] - v;
    if (t < NB2) { bbase[t] = excl; bcur[t] = excl; }
    if (t == NB2 - 1) bbase[NB2] = excl + v;   // == NE
}

__global__ __launch_bounds__(256) void scatter2_kernel(const int* __restrict__ esrc,
                                                       const int* __restrict__ edst,
                                                       int* __restrict__ bcur,
                                                       int2* __restrict__ ebuf) {
    __shared__ int h[NB2];
    __shared__ int cur[NB2];
    for (int i = threadIdx.x; i < NB2; i += 256) h[i] = 0;
    __syncthreads();
    const int base = blockIdx.x * TILE;
    #pragma unroll
    for (int j = 0; j < 16; ++j) {
        int e = base + j * 256 + threadIdx.x;
        if (e < NE) atomicAdd(&h[edst[e] >> 8], 1);
    }
    __syncthreads();
    for (int i = threadIdx.x; i < NB2; i += 256) {
        int c = h[i];
        cur[i] = c ? atomicAdd(&bcur[i], c) : 0;
    }
    __syncthreads();
    #pragma unroll
    for (int j = 0; j < 16; ++j) {
        int e = base + j * 256 + threadIdx.x;
        if (e < NE) {
            int s = esrc[e], d = edst[e];
            int pos = atomicAdd(&cur[d >> 8], 1);
            ebuf[pos] = make_int2(s, d);
        }
    }
}

__global__ __launch_bounds__(256) void csrfill2_kernel(const int2* __restrict__ ebuf,
                                                       const int* __restrict__ bbase,
                                                       int* __restrict__ rp,
                                                       float* __restrict__ dinv,
                                                       int* __restrict__ col) {
    __shared__ int cnt[256];
    __shared__ int cursor[256];
    __shared__ int s[256];
    __shared__ int sbeg, send;
    const int b = blockIdx.x;
    const int t = threadIdx.x;
    if (t == 0) { sbeg = bbase[b]; send = bbase[b + 1]; }
    cnt[t] = 0;
    __syncthreads();
    const int beg = sbeg, end = send;
    const int node0 = b * BKN;

    for (int e = beg + t; e < end; e += 256)
        atomicAdd(&cnt[ebuf[e].y & 255], 1);
    __syncthreads();

    int v = cnt[t];
    s[t] = v;
    __syncthreads();
    for (int off = 1; off < 256; off <<= 1) {
        int a = (t >= off) ? s[t - off] : 0;
        __syncthreads();
        s[t] += a;
        __syncthreads();
    }
    int excl = s[t] - v;
    int gnode = node0 + t;
    if (gnode < NN) {
        rp[gnode]   = beg + excl;
        dinv[gnode] = rsqrtf((float)(v + 1));   // +1 self loop
    }
    cursor[t] = beg + excl;
    if (b == NB2 - 1 && t == 0) rp[NN] = NE;
    __syncthreads();

    for (int e = beg + t; e < end; e += 256) {
        int2 sd = ebuf[e];
        int pos = atomicAdd(&cursor[sd.y & 255], 1);
        col[pos] = sd.x;
    }
}

// ---------------- GEMM:  Hb[n][h*64 + 64 cols] = bf16( (X[n][:] @ W) * scale ) ----------------
__global__ __launch_bounds__(256) void gemm_kernel(const float* __restrict__ X,
                                                   const float* __restrict__ W0,
                                                   const float* __restrict__ W1,
                                                   int wstride,
                                                   const float* __restrict__ dinv,
                                                   int scaleMask,
                                                   unsigned short* __restrict__ Hb) {
    __shared__ float sW[128][64];
    __shared__ float sX[64][132];   // padded: 132 % 32 == 4 -> 2-way (free) on reads

    const int t = threadIdx.x;
    const int h = blockIdx.y;
    const float* __restrict__ W = h ? W1 : W0;
    const bool doScale = (scaleMask >> h) & 1;

    // load W slice: 128 x 64
    #pragma unroll
    for (int i = 0; i < 8; ++i) {
        int e = t * 4 + i * 1024;
        int k = e >> 6, c = e & 63;
        float4 w = *(const float4*)&W[(size_t)k * wstride + c];
        *(float4*)&sW[k][c] = w;
    }
    // load X tile: 64 nodes x 128
    const int tileBase = blockIdx.x * 64;
    #pragma unroll
    for (int i = 0; i < 8; ++i) {
        int e = t * 4 + i * 1024;
        int node = e >> 7, k = e & 127;
        int gn = tileBase + node;
        float4 v = make_float4(0.f, 0.f, 0.f, 0.f);
        if (gn < NN) v = *(const float4*)&X[(size_t)gn * 128 + k];
        *(float4*)&sX[node][k] = v;
    }
    __syncthreads();

    const int tx = t & 15;    // out group: cols tx*4 .. tx*4+3
    const int ty = t >> 4;    // node group: nodes ty*4 .. ty*4+3

    float acc[4][4];
    #pragma unroll
    for (int r = 0; r < 4; ++r)
        #pragma unroll
        for (int c = 0; c < 4; ++c) acc[r][c] = 0.f;

    #pragma unroll 4
    for (int k = 0; k < 128; k += 4) {
        float4 xr[4], wr[4];
        #pragma unroll
        for (int r = 0; r < 4; ++r) xr[r] = *(const float4*)&sX[ty * 4 + r][k];
        #pragma unroll
        for (int j = 0; j < 4; ++j) wr[j] = *(const float4*)&sW[k + j][tx * 4];
        #pragma unroll
        for (int r = 0; r < 4; ++r) {
            #pragma unroll
            for (int j = 0; j < 4; ++j) {
                float xv = (j == 0) ? xr[r].x : (j == 1) ? xr[r].y : (j == 2) ? xr[r].z : xr[r].w;
                acc[r][0] += xv * wr[j].x;
                acc[r][1] += xv * wr[j].y;
                acc[r][2] += xv * wr[j].z;
                acc[r][3] += xv * wr[j].w;
            }
        }
    }

    #pragma unroll
    for (int r = 0; r < 4; ++r) {
        int gn = tileBase + ty * 4 + r;
        if (gn < NN) {
            float s = doScale ? dinv[gn] : 1.f;
            ushort4 o;
            o.x = f2bf(acc[r][0] * s);
            o.y = f2bf(acc[r][1] * s);
            o.z = f2bf(acc[r][2] * s);
            o.w = f2bf(acc[r][3] * s);
            *(ushort4*)&Hb[(size_t)gn * 128 + h * 64 + tx * 4] = o;
        }
    }
}

// ---------------- aggregation: 128-feature layers (conv + bias + residual + relu) ----------------
// Hb rows (bf16) are prescaled by dinv[row]; out = relu(dinv[i]*(H[i] + sum_e H[col[e]]) + bias + Xold)
__global__ __launch_bounds__(256) void agg128_kernel(const unsigned short* __restrict__ Hb,
                                                     const float* __restrict__ Xold,
                                                     const int* __restrict__ rp,
                                                     const int* __restrict__ col,
                                                     const float* __restrict__ dinv,
                                                     const float* __restrict__ bias,
                                                     float* __restrict__ Xnew) {
    const int wid  = threadIdx.x >> 6;
    const int lane = threadIdx.x & 63;
    const int i = blockIdx.x * 4 + wid;
    if (i >= NN) return;

    const unsigned int* __restrict__ Hu = (const unsigned int*)Hb;   // 2 bf16 per uint

    const float di = dinv[i];
    const float2 b2 = ((const float2*)bias)[lane];
    const float2 xo = ((const float2*)Xold)[(size_t)i * 64 + lane];

    unsigned int us = Hu[(size_t)i * 64 + lane];   // self term
    float ax = bflo(us), ay = bfhi(us);

    const int beg = rp[i], end = rp[i + 1];
    int e = beg;
    for (; e + 8 <= end; e += 8) {
        int s0 = col[e],     s1 = col[e + 1], s2 = col[e + 2], s3 = col[e + 3];
        int s4 = col[e + 4], s5 = col[e + 5], s6 = col[e + 6], s7 = col[e + 7];
        unsigned int u0 = Hu[(size_t)s0 * 64 + lane];
        unsigned int u1 = Hu[(size_t)s1 * 64 + lane];
        unsigned int u2 = Hu[(size_t)s2 * 64 + lane];
        unsigned int u3 = Hu[(size_t)s3 * 64 + lane];
        unsigned int u4 = Hu[(size_t)s4 * 64 + lane];
        unsigned int u5 = Hu[(size_t)s5 * 64 + lane];
        unsigned int u6 = Hu[(size_t)s6 * 64 + lane];
        unsigned int u7 = Hu[(size_t)s7 * 64 + lane];
        ax += ((bflo(u0) + bflo(u1)) + (bflo(u2) + bflo(u3))) +
              ((bflo(u4) + bflo(u5)) + (bflo(u6) + bflo(u7)));
        ay += ((bfhi(u0) + bfhi(u1)) + (bfhi(u2) + bfhi(u3))) +
              ((bfhi(u4) + bfhi(u5)) + (bfhi(u6) + bfhi(u7)));
    }
    for (; e + 4 <= end; e += 4) {
        int s0 = col[e], s1 = col[e + 1], s2 = col[e + 2], s3 = col[e + 3];
        unsigned int u0 = Hu[(size_t)s0 * 64 + lane];
        unsigned int u1 = Hu[(size_t)s1 * 64 + lane];
        unsigned int u2 = Hu[(size_t)s2 * 64 + lane];
        unsigned int u3 = Hu[(size_t)s3 * 64 + lane];
        ax += (bflo(u0) + bflo(u1)) + (bflo(u2) + bflo(u3));
        ay += (bfhi(u0) + bfhi(u1)) + (bfhi(u2) + bfhi(u3));
    }
    for (; e < end; ++e) {
        unsigned int u = Hu[(size_t)col[e] * 64 + lane];
        ax += bflo(u);
        ay += bfhi(u);
    }

    float ox = fmaxf(di * ax + b2.x + xo.x, 0.f);
    float oy = fmaxf(di * ay + b2.y + xo.y, 0.f);
    ((float2*)Xnew)[(size_t)i * 64 + lane] = make_float2(ox, oy);
}

// ---------------- final layer: 64-feature conv + bias + skip ----------------
// Hb rows: cols 0..63 = x@W_out (prescaled, bf16), cols 64..127 = x@W_skip_out (raw, bf16)
__global__ __launch_bounds__(256) void aggout_kernel(const unsigned short* __restrict__ Hb,
                                                     const int* __restrict__ rp,
                                                     const int* __restrict__ col,
                                                     const float* __restrict__ dinv,
                                                     const float* __restrict__ bias,
                                                     float* __restrict__ out) {
    const int wid  = threadIdx.x >> 6;
    const int lane = threadIdx.x & 63;
    const int i = blockIdx.x * 4 + wid;
    if (i >= NN) return;

    const float di = dinv[i];
    const float b  = bias[lane];
    const float sk = bf2f(Hb[(size_t)i * 128 + 64 + lane]);   // skip projection (unscaled)

    float a = bf2f(Hb[(size_t)i * 128 + lane]);               // self term
    const int beg = rp[i], end = rp[i + 1];
    int e = beg;
    for (; e + 8 <= end; e += 8) {
        int s0 = col[e],     s1 = col[e + 1], s2 = col[e + 2], s3 = col[e + 3];
        int s4 = col[e + 4], s5 = col[e + 5], s6 = col[e + 6], s7 = col[e + 7];
        float m0 = bf2f(Hb[(size_t)s0 * 128 + lane]);
        float m1 = bf2f(Hb[(size_t)s1 * 128 + lane]);
        float m2 = bf2f(Hb[(size_t)s2 * 128 + lane]);
        float m3 = bf2f(Hb[(size_t)s3 * 128 + lane]);
        float m4 = bf2f(Hb[(size_t)s4 * 128 + lane]);
        float m5 = bf2f(Hb[(size_t)s5 * 128 + lane]);
        float m6 = bf2f(Hb[(size_t)s6 * 128 + lane]);
        float m7 = bf2f(Hb[(size_t)s7 * 128 + lane]);
        a += ((m0 + m1) + (m2 + m3)) + ((m4 + m5) + (m6 + m7));
    }
    for (; e + 4 <= end; e += 4) {
        int s0 = col[e], s1 = col[e + 1], s2 = col[e + 2], s3 = col[e + 3];
        float m0 = bf2f(Hb[(size_t)s0 * 128 + lane]);
        float m1 = bf2f(Hb[(size_t)s1 * 128 + lane]);
        float m2 = bf2f(Hb[(size_t)s2 * 128 + lane]);
        float m3 = bf2f(Hb[(size_t)s3 * 128 + lane]);
        a += (m0 + m1) + (m2 + m3);
    }
    for (; e < end; ++e) a += bf2f(Hb[(size_t)col[e] * 128 + lane]);

    out[(size_t)i * 64 + lane] = di * a + b + sk;
}

// ---------------- launch ----------------
extern "C" void kernel_launch(void* const* d_in, const int* in_sizes, int n_in,
                              void* d_out, int out_size, void* d_ws, size_t ws_size,
                              hipStream_t stream) {
    const float* x      = (const float*)d_in[0];
    const int*   ei     = (const int*)d_in[1];
    const float* W_in   = (const float*)d_in[2];
    const float* b_in   = (const float*)d_in[3];
    const float* W_mid0 = (const float*)d_in[4];
    const float* b_mid0 = (const float*)d_in[5];
    const float* W_mid1 = (const float*)d_in[6];
    const float* b_mid1 = (const float*)d_in[7];
    const float* W_out  = (const float*)d_in[8];
    const float* b_out  = (const float*)d_in[9];
    const float* W_skip = (const float*)d_in[10];

    const int* esrc = ei;        // edge_index[0]
    const int* edst = ei + NE;   // edge_index[1]

    char* ws = (char*)d_ws;
    int*   bcnt   = (int*)  (ws + OFF_BCNT);
    int*   bbase  = (int*)  (ws + OFF_BBASE);
    int*   bcur   = (int*)  (ws + OFF_BCUR);
    int*   rp     = (int*)  (ws + OFF_RP);
    float* dinv   = (float*)(ws + OFF_DINV);
    int*   col    = (int*)  (ws + OFF_COL);
    unsigned short* hbuf = (unsigned short*)(ws + OFF_H);
    int2*  ebuf   = (int2*) (ws + OFF_H);    // alias: dead before first GEMM
    float* xbuf   = (float*)(ws + OFF_X);
    float* outp   = (float*)d_out;

    const dim3 gemmGrid((NN + 63) / 64, 2);          // 1563 x 2
    const int aggGrid = (NN + 3) / 4;                // 25000

    // ---- graph preprocessing (every call: ws is not re-initialized by harness) ----
    hipMemsetAsync(bcnt, 0, (size_t)(NB2 + 1) * 4, stream);
    bhist_kernel<<<NT, 256, 0, stream>>>(edst, bcnt);
    bscan_kernel<<<1, 512, 0, stream>>>(bcnt, bbase, bcur);
    scatter2_kernel<<<NT, 256, 0, stream>>>(esrc, edst, bcur, ebuf);
    csrfill2_kernel<<<NB2, 256, 0, stream>>>(ebuf, bbase, rp, dinv, col);

    // ---- layer 1 (reads input x, writes xbuf) ----
    gemm_kernel<<<gemmGrid, 256, 0, stream>>>(x, W_in, W_in + 64, 128, dinv, 3, hbuf);
    agg128_kernel<<<aggGrid, 256, 0, stream>>>(hbuf, x, rp, col, dinv, b_in, xbuf);

    // ---- layer 2 ----
    gemm_kernel<<<gemmGrid, 256, 0, stream>>>(xbuf, W_mid0, W_mid0 + 64, 128, dinv, 3, hbuf);
    agg128_kernel<<<aggGrid, 256, 0, stream>>>(hbuf, xbuf, rp, col, dinv, b_mid0, xbuf);

    // ---- layer 3 ----
    gemm_kernel<<<gemmGrid, 256, 0, stream>>>(xbuf, W_mid1, W_mid1 + 64, 128, dinv, 3, hbuf);
    agg128_kernel<<<aggGrid, 256, 0, stream>>>(hbuf, xbuf, rp, col, dinv, b_mid1, xbuf);

    // ---- layer 4: fused [W_out | W_skip_out] GEMM (scale only W_out half), then conv+bias+skip ----
    gemm_kernel<<<gemmGrid, 256, 0, stream>>>(xbuf, W_out, W_skip, 64, dinv, 1, hbuf);
    aggout_kernel<<<aggGrid, 256, 0, stream>>>(hbuf, rp, col, dinv, b_out, outp);
}

// Round 7
// 416.633 us; speedup vs baseline: 2.8597x; 1.3676x over previous
//
#include <hip/hip_runtime.h>
#include <hip/hip_bf16.h>

// ---------------- problem constants ----------------
constexpr int NN = 100000;   // nodes
constexpr int NE = 1600000;  // directed edges
constexpr int NH = 128;      // hidden width (== n_feat)
constexpr int NC = 64;       // classes
constexpr int BKN  = 256;                  // nodes per bucket
constexpr int NB2  = (NN + BKN - 1) / BKN; // 391 buckets
constexpr int TILE = 4096;                 // edges per scatter block
constexpr int NT   = (NE + TILE - 1) / TILE; // 391 tiles

// ---------------- bf16 helpers (RNE) ----------------
__device__ __forceinline__ unsigned short f2bf(float f) {
    unsigned int u = __float_as_uint(f);
    unsigned int r = (u + 0x7fffu + ((u >> 16) & 1u)) >> 16;
    return (unsigned short)r;
}
__device__ __forceinline__ float bflo(unsigned int u) { return __uint_as_float(u << 16); }
__device__ __forceinline__ float bfhi(unsigned int u) { return __uint_as_float(u & 0xffff0000u); }
__device__ __forceinline__ float bf2f(unsigned short h) { return __uint_as_float(((unsigned int)h) << 16); }

typedef __bf16 v8bf __attribute__((ext_vector_type(8)));
typedef float  v4f  __attribute__((ext_vector_type(4)));

// ---------------- workspace layout (bytes) ----------------
constexpr size_t OFF_BCNT  = 0;                         // NB2+1 ints
constexpr size_t OFF_BBASE = OFF_BCNT  + 2048;          // NB2+1 ints
constexpr size_t OFF_BCUR  = OFF_BBASE + 2048;          // NB2 ints
constexpr size_t OFF_RP    = OFF_BCUR  + 2048;          // NN+1 ints
constexpr size_t OFF_DINV  = OFF_RP    + 400384;        // NN floats
constexpr size_t OFF_COL   = OFF_DINV  + 400384;        // E ints
constexpr size_t OFF_WT    = OFF_COL   + 6400000;       // 128x128 bf16 (W^T, per-layer)
constexpr size_t OFF_H     = OFF_WT    + 32768;         // N*128 bf16 (prescaled; aliased as ebuf in preproc)
constexpr size_t OFF_X     = OFF_H     + 25600000;      // N*128 floats
// ebuf (E int2 = 12.8 MB) aliases OFF_H (25.6 MB region; dead until first GEMM)

// ---------------- preprocessing: radix-partition CSR build ----------------

__global__ __launch_bounds__(256) void bhist_kernel(const int* __restrict__ edst,
                                                    int* __restrict__ bcnt) {
    __shared__ int h[NB2];
    for (int i = threadIdx.x; i < NB2; i += 256) h[i] = 0;
    __syncthreads();
    const int base = blockIdx.x * TILE;
    #pragma unroll
    for (int j = 0; j < 16; ++j) {
        int e = base + j * 256 + threadIdx.x;
        if (e < NE) atomicAdd(&h[edst[e] >> 8], 1);
    }
    __syncthreads();
    for (int i = threadIdx.x; i < NB2; i += 256)
        if (h[i]) atomicAdd(&bcnt[i], h[i]);
}

__global__ __launch_bounds__(512) void bscan_kernel(const int* __restrict__ bcnt,
                                                    int* __restrict__ bbase,
                                                    int* __restrict__ bcur) {
    __shared__ int s[512];
    const int t = threadIdx.x;
    int v = (t < NB2) ? bcnt[t] : 0;
    s[t] = v;
    __syncthreads();
    for (int off = 1; off < 512; off <<= 1) {
        int a = (t >= off) ? s[t - off] : 0;
        __syncthreads();
        s[t] += a;
        __syncthreads();
    }
    int excl = s[t] - v;
    if (t < NB2) { bbase[t] = excl; bcur[t] = excl; }
    if (t == NB2 - 1) bbase[NB2] = excl + v;   // == NE
}

__global__ __launch_bounds__(256) void scatter2_kernel(const int* __restrict__ esrc,
                                                       const int* __restrict__ edst,
                                                       int* __restrict__ bcur,
                                                       int2* __restrict__ ebuf) {
    __shared__ int h[NB2];
    __shared__ int cur[NB2];
    for (int i = threadIdx.x; i < NB2; i += 256) h[i] = 0;
    __syncthreads();
    const int base = blockIdx.x * TILE;
    #pragma unroll
    for (int j = 0; j < 16; ++j) {
        int e = base + j * 256 + threadIdx.x;
        if (e < NE) atomicAdd(&h[edst[e] >> 8], 1);
    }
    __syncthreads();
    for (int i = threadIdx.x; i < NB2; i += 256) {
        int c = h[i];
        cur[i] = c ? atomicAdd(&bcur[i], c) : 0;
    }
    __syncthreads();
    #pragma unroll
    for (int j = 0; j < 16; ++j) {
        int e = base + j * 256 + threadIdx.x;
        if (e < NE) {
            int s = esrc[e], d = edst[e];
            int pos = atomicAdd(&cur[d >> 8], 1);
            ebuf[pos] = make_int2(s, d);
        }
    }
}

__global__ __launch_bounds__(256) void csrfill2_kernel(const int2* __restrict__ ebuf,
                                                       const int* __restrict__ bbase,
                                                       int* __restrict__ rp,
                                                       float* __restrict__ dinv,
                                                       int* __restrict__ col) {
    __shared__ int cnt[256];
    __shared__ int cursor[256];
    __shared__ int s[256];
    __shared__ int sbeg, send;
    const int b = blockIdx.x;
    const int t = threadIdx.x;
    if (t == 0) { sbeg = bbase[b]; send = bbase[b + 1]; }
    cnt[t] = 0;
    __syncthreads();
    const int beg = sbeg, end = send;
    const int node0 = b * BKN;

    for (int e = beg + t; e < end; e += 256)
        atomicAdd(&cnt[ebuf[e].y & 255], 1);
    __syncthreads();

    int v = cnt[t];
    s[t] = v;
    __syncthreads();
    for (int off = 1; off < 256; off <<= 1) {
        int a = (t >= off) ? s[t - off] : 0;
        __syncthreads();
        s[t] += a;
        __syncthreads();
    }
    int excl = s[t] - v;
    int gnode = node0 + t;
    if (gnode < NN) {
        rp[gnode]   = beg + excl;
        dinv[gnode] = rsqrtf((float)(v + 1));   // +1 self loop
    }
    cursor[t] = beg + excl;
    if (b == NB2 - 1 && t == 0) rp[NN] = NE;
    __syncthreads();

    for (int e = beg + t; e < end; e += 256) {
        int2 sd = ebuf[e];
        int pos = atomicAdd(&cursor[sd.y & 255], 1);
        col[pos] = sd.x;
    }
}

// ---------------- W pre-transpose: Wt[c][k] = bf16(W[k][c]),  c<64 from W0, c>=64 from W1 ----
__global__ __launch_bounds__(256) void wpre_kernel(const float* __restrict__ W0,
                                                   const float* __restrict__ W1,
                                                   int wstride,
                                                   unsigned short* __restrict__ Wt) {
    int e = blockIdx.x * 256 + threadIdx.x;   // grid 64 -> 16384
    int k = e >> 7, c = e & 127;
    float v = (c < 64) ? W0[(size_t)k * wstride + c] : W1[(size_t)k * wstride + (c - 64)];
    Wt[c * 128 + k] = f2bf(v);
}

// ---------------- MFMA GEMM:  Hb[n][:] = bf16( (X[n][:] @ W) * rowScale ) ----------------
// Wt: [128 cols][128 k] bf16.  Block = 4 waves x 16 rows = 64 rows.
// scaleMask bit h (h = col/64): multiply that half by dinv[row].
constexpr int XROW = 136;   // padded shorts per LDS row (272 B: 2-way banks = free)

__global__ __launch_bounds__(256) void gemm_mfma_kernel(const float* __restrict__ X,
                                                        const unsigned short* __restrict__ Wt,
                                                        const float* __restrict__ dinv,
                                                        int scaleMask,
                                                        unsigned short* __restrict__ Hb) {
    __shared__ unsigned short Wl[128 * XROW];   // W^T staged: [col][k]
    __shared__ unsigned short Xl[64 * XROW];    // X tile bf16: [row][k]; reused for output staging

    const int t = threadIdx.x;
    const int rowBase = blockIdx.x * 64;

    // stage Wt -> LDS (16B chunks, coalesced; 2-way banks): 128 rows x 16 chunks
    #pragma unroll
    for (int i = 0; i < 8; ++i) {
        int f = i * 256 + t;
        int r = f >> 4, c8 = f & 15;
        uint4 w = *(const uint4*)&Wt[r * 128 + c8 * 8];
        *(uint4*)&Wl[r * XROW + c8 * 8] = w;
    }
    // stage X tile -> LDS bf16: 64 rows x 32 float4
    #pragma unroll
    for (int i = 0; i < 8; ++i) {
        int f = i * 256 + t;
        int r = f >> 5, c4 = f & 31;
        int gn = rowBase + r;
        float4 v = make_float4(0.f, 0.f, 0.f, 0.f);
        if (gn < NN) v = *(const float4*)&X[(size_t)gn * 128 + c4 * 4];
        ushort4 o;
        o.x = f2bf(v.x); o.y = f2bf(v.y); o.z = f2bf(v.z); o.w = f2bf(v.w);
        *(ushort4*)&Xl[r * XROW + c4 * 4] = o;
    }
    __syncthreads();

    const int w  = t >> 6;        // wave id: rows w*16 .. w*16+15
    const int l  = t & 63;
    const int lr = l & 15;        // A row / B col within 16
    const int lk = (l >> 4) * 8;  // k sub-offset within each 32-k step

    v4f acc[8];
    #pragma unroll
    for (int n = 0; n < 8; ++n) acc[n] = (v4f){0.f, 0.f, 0.f, 0.f};

    const unsigned short* ax = &Xl[(w * 16 + lr) * XROW + lk];
    const unsigned short* bx = &Wl[lr * XROW + lk];

    #pragma unroll
    for (int kk = 0; kk < 4; ++kk) {
        v8bf a = *(const v8bf*)&ax[kk * 32];
        #pragma unroll
        for (int n = 0; n < 8; ++n) {
            v8bf b = *(const v8bf*)&bx[(n * 16) * XROW + kk * 32];
            acc[n] = __builtin_amdgcn_mfma_f32_16x16x32_bf16(a, b, acc[n], 0, 0, 0);
        }
    }

    // epilogue: scale rows, pack bf16 into own wave's Xl slice (D: col=l&15, row=(l>>4)*4+reg)
    #pragma unroll
    for (int r_ = 0; r_ < 4; ++r_) {
        int row  = w * 16 + (l >> 4) * 4 + r_;
        int grow = rowBase + row;
        float dsc = dinv[grow < NN ? grow : NN - 1];
        #pragma unroll
        for (int n = 0; n < 8; ++n) {
            float sc = ((scaleMask >> (n >> 2)) & 1) ? dsc : 1.f;
            Xl[row * XROW + n * 16 + lr] = f2bf(acc[n][r_] * sc);
        }
    }
    __syncthreads();

    // coalesced store: 64 rows x 16 chunks = 1024 thread-iterations -> i < 4 (NOT 8!)
    #pragma unroll
    for (int i = 0; i < 4; ++i) {
        int f = i * 256 + t;
        int r = f >> 4, c8 = f & 15;
        int gn = rowBase + r;
        if (gn < NN) {
            uint4 v = *(const uint4*)&Xl[r * XROW + c8 * 8];
            *(uint4*)&Hb[(size_t)gn * 128 + c8 * 8] = v;
        }
    }
}

// ---------------- aggregation: 128-feature layers (conv + bias + residual + relu) ----------------
__global__ __launch_bounds__(256) void agg128_kernel(const unsigned short* __restrict__ Hb,
                                                     const float* __restrict__ Xold,
                                                     const int* __restrict__ rp,
                                                     const int* __restrict__ col,
                                                     const float* __restrict__ dinv,
                                                     const float* __restrict__ bias,
                                                     float* __restrict__ Xnew) {
    const int wid  = threadIdx.x >> 6;
    const int lane = threadIdx.x & 63;
    const int i = blockIdx.x * 4 + wid;
    if (i >= NN) return;

    const unsigned int* __restrict__ Hu = (const unsigned int*)Hb;   // 2 bf16 per uint

    const float di = dinv[i];
    const float2 b2 = ((const float2*)bias)[lane];
    const float2 xo = ((const float2*)Xold)[(size_t)i * 64 + lane];

    unsigned int us = Hu[(size_t)i * 64 + lane];   // self term
    float ax = bflo(us), ay = bfhi(us);

    const int beg = rp[i], end = rp[i + 1];
    int e = beg;
    for (; e + 8 <= end; e += 8) {
        int s0 = col[e],     s1 = col[e + 1], s2 = col[e + 2], s3 = col[e + 3];
        int s4 = col[e + 4], s5 = col[e + 5], s6 = col[e + 6], s7 = col[e + 7];
        unsigned int u0 = Hu[(size_t)s0 * 64 + lane];
        unsigned int u1 = Hu[(size_t)s1 * 64 + lane];
        unsigned int u2 = Hu[(size_t)s2 * 64 + lane];
        unsigned int u3 = Hu[(size_t)s3 * 64 + lane];
        unsigned int u4 = Hu[(size_t)s4 * 64 + lane];
        unsigned int u5 = Hu[(size_t)s5 * 64 + lane];
        unsigned int u6 = Hu[(size_t)s6 * 64 + lane];
        unsigned int u7 = Hu[(size_t)s7 * 64 + lane];
        ax += ((bflo(u0) + bflo(u1)) + (bflo(u2) + bflo(u3))) +
              ((bflo(u4) + bflo(u5)) + (bflo(u6) + bflo(u7)));
        ay += ((bfhi(u0) + bfhi(u1)) + (bfhi(u2) + bfhi(u3))) +
              ((bfhi(u4) + bfhi(u5)) + (bfhi(u6) + bfhi(u7)));
    }
    for (; e + 4 <= end; e += 4) {
        int s0 = col[e], s1 = col[e + 1], s2 = col[e + 2], s3 = col[e + 3];
        unsigned int u0 = Hu[(size_t)s0 * 64 + lane];
        unsigned int u1 = Hu[(size_t)s1 * 64 + lane];
        unsigned int u2 = Hu[(size_t)s2 * 64 + lane];
        unsigned int u3 = Hu[(size_t)s3 * 64 + lane];
        ax += (bflo(u0) + bflo(u1)) + (bflo(u2) + bflo(u3));
        ay += (bfhi(u0) + bfhi(u1)) + (bfhi(u2) + bfhi(u3));
    }
    for (; e < end; ++e) {
        unsigned int u = Hu[(size_t)col[e] * 64 + lane];
        ax += bflo(u);
        ay += bfhi(u);
    }

    float ox = fmaxf(di * ax + b2.x + xo.x, 0.f);
    float oy = fmaxf(di * ay + b2.y + xo.y, 0.f);
    ((float2*)Xnew)[(size_t)i * 64 + lane] = make_float2(ox, oy);
}

// ---------------- final layer: 64-feature conv + bias + skip ----------------
__global__ __launch_bounds__(256) void aggout_kernel(const unsigned short* __restrict__ Hb,
                                                     const int* __restrict__ rp,
                                                     const int* __restrict__ col,
                                                     const float* __restrict__ dinv,
                                                     const float* __restrict__ bias,
                                                     float* __restrict__ out) {
    const int wid  = threadIdx.x >> 6;
    const int lane = threadIdx.x & 63;
    const int i = blockIdx.x * 4 + wid;
    if (i >= NN) return;

    const float di = dinv[i];
    const float b  = bias[lane];
    const float sk = bf2f(Hb[(size_t)i * 128 + 64 + lane]);   // skip projection (unscaled)

    float a = bf2f(Hb[(size_t)i * 128 + lane]);               // self term
    const int beg = rp[i], end = rp[i + 1];
    int e = beg;
    for (; e + 8 <= end; e += 8) {
        int s0 = col[e],     s1 = col[e + 1], s2 = col[e + 2], s3 = col[e + 3];
        int s4 = col[e + 4], s5 = col[e + 5], s6 = col[e + 6], s7 = col[e + 7];
        float m0 = bf2f(Hb[(size_t)s0 * 128 + lane]);
        float m1 = bf2f(Hb[(size_t)s1 * 128 + lane]);
        float m2 = bf2f(Hb[(size_t)s2 * 128 + lane]);
        float m3 = bf2f(Hb[(size_t)s3 * 128 + lane]);
        float m4 = bf2f(Hb[(size_t)s4 * 128 + lane]);
        float m5 = bf2f(Hb[(size_t)s5 * 128 + lane]);
        float m6 = bf2f(Hb[(size_t)s6 * 128 + lane]);
        float m7 = bf2f(Hb[(size_t)s7 * 128 + lane]);
        a += ((m0 + m1) + (m2 + m3)) + ((m4 + m5) + (m6 + m7));
    }
    for (; e + 4 <= end; e += 4) {
        int s0 = col[e], s1 = col[e + 1], s2 = col[e + 2], s3 = col[e + 3];
        float m0 = bf2f(Hb[(size_t)s0 * 128 + lane]);
        float m1 = bf2f(Hb[(size_t)s1 * 128 + lane]);
        float m2 = bf2f(Hb[(size_t)s2 * 128 + lane]);
        float m3 = bf2f(Hb[(size_t)s3 * 128 + lane]);
        a += (m0 + m1) + (m2 + m3);
    }
    for (; e < end; ++e) a += bf2f(Hb[(size_t)col[e] * 128 + lane]);

    out[(size_t)i * 64 + lane] = di * a + b + sk;
}

// ---------------- launch ----------------
extern "C" void kernel_launch(void* const* d_in, const int* in_sizes, int n_in,
                              void* d_out, int out_size, void* d_ws, size_t ws_size,
                              hipStream_t stream) {
    const float* x      = (const float*)d_in[0];
    const int*   ei     = (const int*)d_in[1];
    const float* W_in   = (const float*)d_in[2];
    const float* b_in   = (const float*)d_in[3];
    const float* W_mid0 = (const float*)d_in[4];
    const float* b_mid0 = (const float*)d_in[5];
    const float* W_mid1 = (const float*)d_in[6];
    const float* b_mid1 = (const float*)d_in[7];
    const float* W_out  = (const float*)d_in[8];
    const float* b_out  = (const float*)d_in[9];
    const float* W_skip = (const float*)d_in[10];

    const int* esrc = ei;        // edge_index[0]
    const int* edst = ei + NE;   // edge_index[1]

    char* ws = (char*)d_ws;
    int*   bcnt   = (int*)  (ws + OFF_BCNT);
    int*   bbase  = (int*)  (ws + OFF_BBASE);
    int*   bcur   = (int*)  (ws + OFF_BCUR);
    int*   rp     = (int*)  (ws + OFF_RP);
    float* dinv   = (float*)(ws + OFF_DINV);
    int*   col    = (int*)  (ws + OFF_COL);
    unsigned short* wt   = (unsigned short*)(ws + OFF_WT);
    unsigned short* hbuf = (unsigned short*)(ws + OFF_H);
    int2*  ebuf   = (int2*) (ws + OFF_H);    // alias: dead before first GEMM
    float* xbuf   = (float*)(ws + OFF_X);
    float* outp   = (float*)d_out;

    const int gemmGrid = (NN + 63) / 64;             // 1563
    const int aggGrid  = (NN + 3) / 4;               // 25000

    // ---- graph preprocessing (every call: ws is not re-initialized by harness) ----
    hipMemsetAsync(bcnt, 0, (size_t)(NB2 + 1) * 4, stream);
    bhist_kernel<<<NT, 256, 0, stream>>>(edst, bcnt);
    bscan_kernel<<<1, 512, 0, stream>>>(bcnt, bbase, bcur);
    scatter2_kernel<<<NT, 256, 0, stream>>>(esrc, edst, bcur, ebuf);
    csrfill2_kernel<<<NB2, 256, 0, stream>>>(ebuf, bbase, rp, dinv, col);

    // ---- layer 1 (reads input x, writes xbuf) ----
    wpre_kernel<<<64, 256, 0, stream>>>(W_in, W_in + 64, 128, wt);
    gemm_mfma_kernel<<<gemmGrid, 256, 0, stream>>>(x, wt, dinv, 3, hbuf);
    agg128_kernel<<<aggGrid, 256, 0, stream>>>(hbuf, x, rp, col, dinv, b_in, xbuf);

    // ---- layer 2 ----
    wpre_kernel<<<64, 256, 0, stream>>>(W_mid0, W_mid0 + 64, 128, wt);
    gemm_mfma_kernel<<<gemmGrid, 256, 0, stream>>>(xbuf, wt, dinv, 3, hbuf);
    agg128_kernel<<<aggGrid, 256, 0, stream>>>(hbuf, xbuf, rp, col, dinv, b_mid0, xbuf);

    // ---- layer 3 ----
    wpre_kernel<<<64, 256, 0, stream>>>(W_mid1, W_mid1 + 64, 128, wt);
    gemm_mfma_kernel<<<gemmGrid, 256, 0, stream>>>(xbuf, wt, dinv, 3, hbuf);
    agg128_kernel<<<aggGrid, 256, 0, stream>>>(hbuf, xbuf, rp, col, dinv, b_mid1, xbuf);

    // ---- layer 4: fused [W_out | W_skip_out] GEMM (scale only W_out half), then conv+bias+skip ----
    wpre_kernel<<<64, 256, 0, stream>>>(W_out, W_skip, 64, wt);
    gemm_mfma_kernel<<<gemmGrid, 256, 0, stream>>>(xbuf, wt, dinv, 1, hbuf);
    aggout_kernel<<<aggGrid, 256, 0, stream>>>(hbuf, rp, col, dinv, b_out, outp);
}

// Round 8
// 385.919 us; speedup vs baseline: 3.0873x; 1.0796x over previous
//
#include <hip/hip_runtime.h>
#include <hip/hip_bf16.h>

// ---------------- problem constants ----------------
constexpr int NN = 100000;   // nodes
constexpr int NE = 1600000;  // directed edges
constexpr int NH = 128;      // hidden width (== n_feat)
constexpr int NC = 64;       // classes
constexpr int BKN  = 256;                  // nodes per bucket
constexpr int NB2  = (NN + BKN - 1) / BKN; // 391 buckets
constexpr int TILE = 4096;                 // edges per scatter block
constexpr int NT   = (NE + TILE - 1) / TILE; // 391 tiles

// ---------------- bf16 helpers (RNE) ----------------
__device__ __forceinline__ unsigned short f2bf(float f) {
    unsigned int u = __float_as_uint(f);
    unsigned int r = (u + 0x7fffu + ((u >> 16) & 1u)) >> 16;
    return (unsigned short)r;
}
__device__ __forceinline__ float bflo(unsigned int u) { return __uint_as_float(u << 16); }
__device__ __forceinline__ float bfhi(unsigned int u) { return __uint_as_float(u & 0xffff0000u); }
__device__ __forceinline__ float bf2f(unsigned short h) { return __uint_as_float(((unsigned int)h) << 16); }
__device__ __forceinline__ unsigned int pack2bf(float lo, float hi) {
    return (unsigned int)f2bf(lo) | ((unsigned int)f2bf(hi) << 16);
}

typedef __bf16 v8bf __attribute__((ext_vector_type(8)));
typedef float  v4f  __attribute__((ext_vector_type(4)));

// ---------------- workspace layout (bytes) ----------------
constexpr size_t OFF_BCNT  = 0;                         // NB2+1 ints
constexpr size_t OFF_BBASE = OFF_BCNT  + 2048;          // NB2+1 ints
constexpr size_t OFF_BCUR  = OFF_BBASE + 2048;          // NB2 ints
constexpr size_t OFF_RP    = OFF_BCUR  + 2048;          // NN+1 ints
constexpr size_t OFF_DINV  = OFF_RP    + 400384;        // NN floats
constexpr size_t OFF_COL   = OFF_DINV  + 400384;        // E ints
constexpr size_t OFF_WT    = OFF_COL   + 6400000;       // 128x128 bf16 (W^T, per-layer)
constexpr size_t OFF_H     = OFF_WT    + 32768;         // N*128 bf16 (prescaled; aliased as ebuf in preproc)
constexpr size_t OFF_X     = OFF_H     + 25600000;      // N*128 bf16 (residual spine)
// ebuf (E int2 = 12.8 MB) aliases OFF_H (25.6 MB region; dead until first GEMM)

// ---------------- preprocessing: radix-partition CSR build ----------------

__global__ __launch_bounds__(256) void bhist_kernel(const int* __restrict__ edst,
                                                    int* __restrict__ bcnt) {
    __shared__ int h[NB2];
    for (int i = threadIdx.x; i < NB2; i += 256) h[i] = 0;
    __syncthreads();
    const int base = blockIdx.x * TILE;
    #pragma unroll
    for (int j = 0; j < 16; ++j) {
        int e = base + j * 256 + threadIdx.x;
        if (e < NE) atomicAdd(&h[edst[e] >> 8], 1);
    }
    __syncthreads();
    for (int i = threadIdx.x; i < NB2; i += 256)
        if (h[i]) atomicAdd(&bcnt[i], h[i]);
}

__global__ __launch_bounds__(512) void bscan_kernel(const int* __restrict__ bcnt,
                                                    int* __restrict__ bbase,
                                                    int* __restrict__ bcur) {
    __shared__ int s[512];
    const int t = threadIdx.x;
    int v = (t < NB2) ? bcnt[t] : 0;
    s[t] = v;
    __syncthreads();
    for (int off = 1; off < 512; off <<= 1) {
        int a = (t >= off) ? s[t - off] : 0;
        __syncthreads();
        s[t] += a;
        __syncthreads();
    }
    int excl = s[t] - v;
    if (t < NB2) { bbase[t] = excl; bcur[t] = excl; }
    if (t == NB2 - 1) bbase[NB2] = excl + v;   // == NE
}

__global__ __launch_bounds__(256) void scatter2_kernel(const int* __restrict__ esrc,
                                                       const int* __restrict__ edst,
                                                       int* __restrict__ bcur,
                                                       int2* __restrict__ ebuf) {
    __shared__ int h[NB2];
    __shared__ int cur[NB2];
    for (int i = threadIdx.x; i < NB2; i += 256) h[i] = 0;
    __syncthreads();
    const int base = blockIdx.x * TILE;
    #pragma unroll
    for (int j = 0; j < 16; ++j) {
        int e = base + j * 256 + threadIdx.x;
        if (e < NE) atomicAdd(&h[edst[e] >> 8], 1);
    }
    __syncthreads();
    for (int i = threadIdx.x; i < NB2; i += 256) {
        int c = h[i];
        cur[i] = c ? atomicAdd(&bcur[i], c) : 0;
    }
    __syncthreads();
    #pragma unroll
    for (int j = 0; j < 16; ++j) {
        int e = base + j * 256 + threadIdx.x;
        if (e < NE) {
            int s = esrc[e], d = edst[e];
            int pos = atomicAdd(&cur[d >> 8], 1);
            ebuf[pos] = make_int2(s, d);
        }
    }
}

__global__ __launch_bounds__(256) void csrfill2_kernel(const int2* __restrict__ ebuf,
                                                       const int* __restrict__ bbase,
                                                       int* __restrict__ rp,
                                                       float* __restrict__ dinv,
                                                       int* __restrict__ col) {
    __shared__ int cnt[256];
    __shared__ int cursor[256];
    __shared__ int s[256];
    __shared__ int sbeg, send;
    const int b = blockIdx.x;
    const int t = threadIdx.x;
    if (t == 0) { sbeg = bbase[b]; send = bbase[b + 1]; }
    cnt[t] = 0;
    __syncthreads();
    const int beg = sbeg, end = send;
    const int node0 = b * BKN;

    for (int e = beg + t; e < end; e += 256)
        atomicAdd(&cnt[ebuf[e].y & 255], 1);
    __syncthreads();

    int v = cnt[t];
    s[t] = v;
    __syncthreads();
    for (int off = 1; off < 256; off <<= 1) {
        int a = (t >= off) ? s[t - off] : 0;
        __syncthreads();
        s[t] += a;
        __syncthreads();
    }
    int excl = s[t] - v;
    int gnode = node0 + t;
    if (gnode < NN) {
        rp[gnode]   = beg + excl;
        dinv[gnode] = rsqrtf((float)(v + 1));   // +1 self loop
    }
    cursor[t] = beg + excl;
    if (b == NB2 - 1 && t == 0) rp[NN] = NE;
    __syncthreads();

    for (int e = beg + t; e < end; e += 256) {
        int2 sd = ebuf[e];
        int pos = atomicAdd(&cursor[sd.y & 255], 1);
        col[pos] = sd.x;
    }
}

// ---------------- W pre-transpose: Wt[c][k] = bf16(W[k][c]),  c<64 from W0, c>=64 from W1 ----
__global__ __launch_bounds__(256) void wpre_kernel(const float* __restrict__ W0,
                                                   const float* __restrict__ W1,
                                                   int wstride,
                                                   unsigned short* __restrict__ Wt) {
    int e = blockIdx.x * 256 + threadIdx.x;   // grid 64 -> 16384
    int k = e >> 7, c = e & 127;
    float v = (c < 64) ? W0[(size_t)k * wstride + c] : W1[(size_t)k * wstride + (c - 64)];
    Wt[c * 128 + k] = f2bf(v);
}

// ---------------- MFMA GEMM:  Hb[n][:] = bf16( (X[n][:] @ W) * rowScale ) ----------------
// XF32: X is fp32 (layer 1 input); else X is bf16 row-major (residual spine).
constexpr int XROW = 136;   // padded shorts per LDS row (272 B: 2-way banks = free)

template<bool XF32>
__global__ __launch_bounds__(256) void gemm_mfma_kernel(const void* __restrict__ Xv,
                                                        const unsigned short* __restrict__ Wt,
                                                        const float* __restrict__ dinv,
                                                        int scaleMask,
                                                        unsigned short* __restrict__ Hb) {
    __shared__ unsigned short Wl[128 * XROW];   // W^T staged: [col][k]
    __shared__ unsigned short Xl[64 * XROW];    // X tile bf16: [row][k]; reused for output staging

    const int t = threadIdx.x;
    const int rowBase = blockIdx.x * 64;

    // stage Wt -> LDS (16B chunks, coalesced): 128 rows x 16 chunks
    #pragma unroll
    for (int i = 0; i < 8; ++i) {
        int f = i * 256 + t;
        int r = f >> 4, c8 = f & 15;
        uint4 w = *(const uint4*)&Wt[r * 128 + c8 * 8];
        *(uint4*)&Wl[r * XROW + c8 * 8] = w;
    }
    // stage X tile -> LDS bf16
    if (XF32) {
        const float* X = (const float*)Xv;
        #pragma unroll
        for (int i = 0; i < 8; ++i) {
            int f = i * 256 + t;                  // 64 rows x 32 float4
            int r = f >> 5, c4 = f & 31;
            int gn = rowBase + r;
            float4 v = make_float4(0.f, 0.f, 0.f, 0.f);
            if (gn < NN) v = *(const float4*)&X[(size_t)gn * 128 + c4 * 4];
            ushort4 o;
            o.x = f2bf(v.x); o.y = f2bf(v.y); o.z = f2bf(v.z); o.w = f2bf(v.w);
            *(ushort4*)&Xl[r * XROW + c4 * 4] = o;
        }
    } else {
        const unsigned short* X = (const unsigned short*)Xv;
        #pragma unroll
        for (int i = 0; i < 4; ++i) {
            int f = i * 256 + t;                  // 64 rows x 16 uint4 chunks
            int r = f >> 4, c8 = f & 15;
            int gn = rowBase + r;
            uint4 v = make_uint4(0u, 0u, 0u, 0u);
            if (gn < NN) v = *(const uint4*)&X[(size_t)gn * 128 + c8 * 8];
            *(uint4*)&Xl[r * XROW + c8 * 8] = v;
        }
    }
    __syncthreads();

    const int w  = t >> 6;        // wave id: rows w*16 .. w*16+15
    const int l  = t & 63;
    const int lr = l & 15;        // A row / B col within 16
    const int lk = (l >> 4) * 8;  // k sub-offset within each 32-k step

    v4f acc[8];
    #pragma unroll
    for (int n = 0; n < 8; ++n) acc[n] = (v4f){0.f, 0.f, 0.f, 0.f};

    const unsigned short* ax = &Xl[(w * 16 + lr) * XROW + lk];
    const unsigned short* bx = &Wl[lr * XROW + lk];

    #pragma unroll
    for (int kk = 0; kk < 4; ++kk) {
        v8bf a = *(const v8bf*)&ax[kk * 32];
        #pragma unroll
        for (int n = 0; n < 8; ++n) {
            v8bf b = *(const v8bf*)&bx[(n * 16) * XROW + kk * 32];
            acc[n] = __builtin_amdgcn_mfma_f32_16x16x32_bf16(a, b, acc[n], 0, 0, 0);
        }
    }

    // epilogue: scale rows, pack bf16 (D: col=l&15, row=(l>>4)*4+reg)
    #pragma unroll
    for (int r_ = 0; r_ < 4; ++r_) {
        int row  = w * 16 + (l >> 4) * 4 + r_;
        int grow = rowBase + row;
        float dsc = dinv[grow < NN ? grow : NN - 1];
        #pragma unroll
        for (int n = 0; n < 8; ++n) {
            float sc = ((scaleMask >> (n >> 2)) & 1) ? dsc : 1.f;
            Xl[row * XROW + n * 16 + lr] = f2bf(acc[n][r_] * sc);
        }
    }
    __syncthreads();

    // coalesced store: 64 rows x 16 chunks
    #pragma unroll
    for (int i = 0; i < 4; ++i) {
        int f = i * 256 + t;
        int r = f >> 4, c8 = f & 15;
        int gn = rowBase + r;
        if (gn < NN) {
            uint4 v = *(const uint4*)&Xl[r * XROW + c8 * 8];
            *(uint4*)&Hb[(size_t)gn * 128 + c8 * 8] = v;
        }
    }
}

// ---------------- aggregation: 128-feature layers (conv + bias + residual + relu) ----------------
// XF32: Xold is fp32 (layer 1 reads input x); else bf16. Xnew always bf16.
template<bool XF32>
__global__ __launch_bounds__(256) void agg128_kernel(const unsigned short* __restrict__ Hb,
                                                     const void* __restrict__ Xoldv,
                                                     const int* __restrict__ rp,
                                                     const int* __restrict__ col,
                                                     const float* __restrict__ dinv,
                                                     const float* __restrict__ bias,
                                                     unsigned int* __restrict__ Xnew) {
    const int wid  = threadIdx.x >> 6;
    const int lane = threadIdx.x & 63;
    const int i = blockIdx.x * 4 + wid;
    if (i >= NN) return;

    const unsigned int* __restrict__ Hu = (const unsigned int*)Hb;   // 2 bf16 per uint

    const float di = dinv[i];
    const float2 b2 = ((const float2*)bias)[lane];
    float xox, xoy;
    if (XF32) {
        float2 xo = ((const float2*)Xoldv)[(size_t)i * 64 + lane];
        xox = xo.x; xoy = xo.y;
    } else {
        unsigned int xo = ((const unsigned int*)Xoldv)[(size_t)i * 64 + lane];
        xox = bflo(xo); xoy = bfhi(xo);
    }

    unsigned int us = Hu[(size_t)i * 64 + lane];   // self term
    float ax = bflo(us), ay = bfhi(us);

    const int beg = rp[i], end = rp[i + 1];
    int e = beg;
    for (; e + 8 <= end; e += 8) {
        int s0 = col[e],     s1 = col[e + 1], s2 = col[e + 2], s3 = col[e + 3];
        int s4 = col[e + 4], s5 = col[e + 5], s6 = col[e + 6], s7 = col[e + 7];
        unsigned int u0 = Hu[(size_t)s0 * 64 + lane];
        unsigned int u1 = Hu[(size_t)s1 * 64 + lane];
        unsigned int u2 = Hu[(size_t)s2 * 64 + lane];
        unsigned int u3 = Hu[(size_t)s3 * 64 + lane];
        unsigned int u4 = Hu[(size_t)s4 * 64 + lane];
        unsigned int u5 = Hu[(size_t)s5 * 64 + lane];
        unsigned int u6 = Hu[(size_t)s6 * 64 + lane];
        unsigned int u7 = Hu[(size_t)s7 * 64 + lane];
        ax += ((bflo(u0) + bflo(u1)) + (bflo(u2) + bflo(u3))) +
              ((bflo(u4) + bflo(u5)) + (bflo(u6) + bflo(u7)));
        ay += ((bfhi(u0) + bfhi(u1)) + (bfhi(u2) + bfhi(u3))) +
              ((bfhi(u4) + bfhi(u5)) + (bfhi(u6) + bfhi(u7)));
    }
    for (; e + 4 <= end; e += 4) {
        int s0 = col[e], s1 = col[e + 1], s2 = col[e + 2], s3 = col[e + 3];
        unsigned int u0 = Hu[(size_t)s0 * 64 + lane];
        unsigned int u1 = Hu[(size_t)s1 * 64 + lane];
        unsigned int u2 = Hu[(size_t)s2 * 64 + lane];
        unsigned int u3 = Hu[(size_t)s3 * 64 + lane];
        ax += (bflo(u0) + bflo(u1)) + (bflo(u2) + bflo(u3));
        ay += (bfhi(u0) + bfhi(u1)) + (bfhi(u2) + bfhi(u3));
    }
    for (; e < end; ++e) {
        unsigned int u = Hu[(size_t)col[e] * 64 + lane];
        ax += bflo(u);
        ay += bfhi(u);
    }

    float ox = fmaxf(di * ax + b2.x + xox, 0.f);
    float oy = fmaxf(di * ay + b2.y + xoy, 0.f);
    Xnew[(size_t)i * 64 + lane] = pack2bf(ox, oy);
}

// ---------------- final layer: 64-feature conv + bias + skip ----------------
__global__ __launch_bounds__(256) void aggout_kernel(const unsigned short* __restrict__ Hb,
                                                     const int* __restrict__ rp,
                                                     const int* __restrict__ col,
                                                     const float* __restrict__ dinv,
                                                     const float* __restrict__ bias,
                                                     float* __restrict__ out) {
    const int wid  = threadIdx.x >> 6;
    const int lane = threadIdx.x & 63;
    const int i = blockIdx.x * 4 + wid;
    if (i >= NN) return;

    const float di = dinv[i];
    const float b  = bias[lane];
    const float sk = bf2f(Hb[(size_t)i * 128 + 64 + lane]);   // skip projection (unscaled)

    float a = bf2f(Hb[(size_t)i * 128 + lane]);               // self term
    const int beg = rp[i], end = rp[i + 1];
    int e = beg;
    for (; e + 8 <= end; e += 8) {
        int s0 = col[e],     s1 = col[e + 1], s2 = col[e + 2], s3 = col[e + 3];
        int s4 = col[e + 4], s5 = col[e + 5], s6 = col[e + 6], s7 = col[e + 7];
        float m0 = bf2f(Hb[(size_t)s0 * 128 + lane]);
        float m1 = bf2f(Hb[(size_t)s1 * 128 + lane]);
        float m2 = bf2f(Hb[(size_t)s2 * 128 + lane]);
        float m3 = bf2f(Hb[(size_t)s3 * 128 + lane]);
        float m4 = bf2f(Hb[(size_t)s4 * 128 + lane]);
        float m5 = bf2f(Hb[(size_t)s5 * 128 + lane]);
        float m6 = bf2f(Hb[(size_t)s6 * 128 + lane]);
        float m7 = bf2f(Hb[(size_t)s7 * 128 + lane]);
        a += ((m0 + m1) + (m2 + m3)) + ((m4 + m5) + (m6 + m7));
    }
    for (; e + 4 <= end; e += 4) {
        int s0 = col[e], s1 = col[e + 1], s2 = col[e + 2], s3 = col[e + 3];
        float m0 = bf2f(Hb[(size_t)s0 * 128 + lane]);
        float m1 = bf2f(Hb[(size_t)s1 * 128 + lane]);
        float m2 = bf2f(Hb[(size_t)s2 * 128 + lane]);
        float m3 = bf2f(Hb[(size_t)s3 * 128 + lane]);
        a += (m0 + m1) + (m2 + m3);
    }
    for (; e < end; ++e) a += bf2f(Hb[(size_t)col[e] * 128 + lane]);

    out[(size_t)i * 64 + lane] = di * a + b + sk;
}

// ---------------- launch ----------------
extern "C" void kernel_launch(void* const* d_in, const int* in_sizes, int n_in,
                              void* d_out, int out_size, void* d_ws, size_t ws_size,
                              hipStream_t stream) {
    const float* x      = (const float*)d_in[0];
    const int*   ei     = (const int*)d_in[1];
    const float* W_in   = (const float*)d_in[2];
    const float* b_in   = (const float*)d_in[3];
    const float* W_mid0 = (const float*)d_in[4];
    const float* b_mid0 = (const float*)d_in[5];
    const float* W_mid1 = (const float*)d_in[6];
    const float* b_mid1 = (const float*)d_in[7];
    const float* W_out  = (const float*)d_in[8];
    const float* b_out  = (const float*)d_in[9];
    const float* W_skip = (const float*)d_in[10];

    const int* esrc = ei;        // edge_index[0]
    const int* edst = ei + NE;   // edge_index[1]

    char* ws = (char*)d_ws;
    int*   bcnt   = (int*)  (ws + OFF_BCNT);
    int*   bbase  = (int*)  (ws + OFF_BBASE);
    int*   bcur   = (int*)  (ws + OFF_BCUR);
    int*   rp     = (int*)  (ws + OFF_RP);
    float* dinv   = (float*)(ws + OFF_DINV);
    int*   col    = (int*)  (ws + OFF_COL);
    unsigned short* wt   = (unsigned short*)(ws + OFF_WT);
    unsigned short* hbuf = (unsigned short*)(ws + OFF_H);
    int2*  ebuf   = (int2*) (ws + OFF_H);    // alias: dead before first GEMM
    unsigned short* xbuf = (unsigned short*)(ws + OFF_X);
    unsigned int*   xbufw = (unsigned int*)(ws + OFF_X);
    float* outp   = (float*)d_out;

    const int gemmGrid = (NN + 63) / 64;             // 1563
    const int aggGrid  = (NN + 3) / 4;               // 25000

    // ---- graph preprocessing (every call: ws is not re-initialized by harness) ----
    hipMemsetAsync(bcnt, 0, (size_t)(NB2 + 1) * 4, stream);
    bhist_kernel<<<NT, 256, 0, stream>>>(edst, bcnt);
    bscan_kernel<<<1, 512, 0, stream>>>(bcnt, bbase, bcur);
    scatter2_kernel<<<NT, 256, 0, stream>>>(esrc, edst, bcur, ebuf);
    csrfill2_kernel<<<NB2, 256, 0, stream>>>(ebuf, bbase, rp, dinv, col);

    // ---- layer 1 (reads input x fp32, writes xbuf bf16) ----
    wpre_kernel<<<64, 256, 0, stream>>>(W_in, W_in + 64, 128, wt);
    gemm_mfma_kernel<true><<<gemmGrid, 256, 0, stream>>>(x, wt, dinv, 3, hbuf);
    agg128_kernel<true><<<aggGrid, 256, 0, stream>>>(hbuf, x, rp, col, dinv, b_in, xbufw);

    // ---- layer 2 ----
    wpre_kernel<<<64, 256, 0, stream>>>(W_mid0, W_mid0 + 64, 128, wt);
    gemm_mfma_kernel<false><<<gemmGrid, 256, 0, stream>>>(xbuf, wt, dinv, 3, hbuf);
    agg128_kernel<false><<<aggGrid, 256, 0, stream>>>(hbuf, xbuf, rp, col, dinv, b_mid0, xbufw);

    // ---- layer 3 ----
    wpre_kernel<<<64, 256, 0, stream>>>(W_mid1, W_mid1 + 64, 128, wt);
    gemm_mfma_kernel<false><<<gemmGrid, 256, 0, stream>>>(xbuf, wt, dinv, 3, hbuf);
    agg128_kernel<false><<<aggGrid, 256, 0, stream>>>(hbuf, xbuf, rp, col, dinv, b_mid1, xbufw);

    // ---- layer 4: fused [W_out | W_skip_out] GEMM (scale only W_out half), then conv+bias+skip ----
    wpre_kernel<<<64, 256, 0, stream>>>(W_out, W_skip, 64, wt);
    gemm_mfma_kernel<false><<<gemmGrid, 256, 0, stream>>>(xbuf, wt, dinv, 1, hbuf);
    aggout_kernel<<<aggGrid, 256, 0, stream>>>(hbuf, rp, col, dinv, b_out, outp);
}

// Round 9
// 339.481 us; speedup vs baseline: 3.5097x; 1.1368x over previous
//
#include <hip/hip_runtime.h>
#include <hip/hip_bf16.h>

// ---------------- problem constants ----------------
constexpr int NN = 100000;   // nodes
constexpr int NE = 1600000;  // directed edges
constexpr int BKN  = 256;                  // nodes per bucket
constexpr int NB2  = (NN + BKN - 1) / BKN; // 391 buckets
constexpr int TILE = 4096;                 // edges per scatter block
constexpr int NT   = (NE + TILE - 1) / TILE; // 391 tiles

// ---------------- bf16 / fp8 helpers ----------------
__device__ __forceinline__ unsigned short f2bf(float f) {
    unsigned int u = __float_as_uint(f);
    unsigned int r = (u + 0x7fffu + ((u >> 16) & 1u)) >> 16;
    return (unsigned short)r;
}
__device__ __forceinline__ float bflo(unsigned int u) { return __uint_as_float(u << 16); }
__device__ __forceinline__ float bfhi(unsigned int u) { return __uint_as_float(u & 0xffff0000u); }
__device__ __forceinline__ float bf2f(unsigned short h) { return __uint_as_float(((unsigned int)h) << 16); }
__device__ __forceinline__ unsigned int pack2bf(float lo, float hi) {
    return (unsigned int)f2bf(lo) | ((unsigned int)f2bf(hi) << 16);
}

typedef __bf16 v8bf __attribute__((ext_vector_type(8)));
typedef float  v4f  __attribute__((ext_vector_type(4)));
typedef float  v2f  __attribute__((ext_vector_type(2)));

__device__ __forceinline__ v2f fp8x2_to_f32(unsigned int u) {
    return __builtin_amdgcn_cvt_pk_f32_fp8(u, false);   // bytes 0,1 -> {x,y}
}

// ---------------- workspace layout (bytes) ----------------
constexpr size_t OFF_BCNT  = 0;                          // NB2+1 ints
constexpr size_t OFF_BBASE = OFF_BCNT  + 2048;           // NB2+1 ints
constexpr size_t OFF_BCUR  = OFF_BBASE + 2048;           // NB2 ints
constexpr size_t OFF_RP    = OFF_BCUR  + 2048;           // NN+1 ints
constexpr size_t OFF_DINV  = OFF_RP    + 400384;         // NN floats
constexpr size_t OFF_COL   = OFF_DINV  + 400384;         // E ints
constexpr size_t OFF_WT    = OFF_COL   + 6400000;        // 128x128 bf16 (W^T per layer)
constexpr size_t OFF_H8    = OFF_WT    + 32768;          // N*128 fp8 (mid-layer messages, prescaled)
constexpr size_t OFF_H     = OFF_H8    + 12800000;       // N*128 bf16 (layer-4 messages; ebuf alias in preproc)
constexpr size_t OFF_X     = OFF_H     + 25600000;       // N*128 bf16 (residual spine)
// ebuf (E uint = 6.4 MB) aliases OFF_H (dead until layer-4 GEMM)

// ---------------- preprocessing: radix-partition CSR build ----------------

__global__ __launch_bounds__(256) void bhist_kernel(const int* __restrict__ edst,
                                                    int* __restrict__ bcnt) {
    __shared__ int h[NB2];
    for (int i = threadIdx.x; i < NB2; i += 256) h[i] = 0;
    __syncthreads();
    const int base = blockIdx.x * TILE;
    #pragma unroll
    for (int j = 0; j < 16; ++j) {
        int e = base + j * 256 + threadIdx.x;
        if (e < NE) atomicAdd(&h[edst[e] >> 8], 1);
    }
    __syncthreads();
    for (int i = threadIdx.x; i < NB2; i += 256)
        if (h[i]) atomicAdd(&bcnt[i], h[i]);
}

__global__ __launch_bounds__(512) void bscan_kernel(const int* __restrict__ bcnt,
                                                    int* __restrict__ bbase,
                                                    int* __restrict__ bcur) {
    __shared__ int s[512];
    const int t = threadIdx.x;
    int v = (t < NB2) ? bcnt[t] : 0;
    s[t] = v;
    __syncthreads();
    for (int off = 1; off < 512; off <<= 1) {
        int a = (t >= off) ? s[t - off] : 0;
        __syncthreads();
        s[t] += a;
        __syncthreads();
    }
    int excl = s[t] - v;
    if (t < NB2) { bbase[t] = excl; bcur[t] = excl; }
    if (t == NB2 - 1) bbase[NB2] = excl + v;   // == NE
}

// edges -> bucket-ordered packed ebuf: src | (dst&255)<<24  (src < 2^17)
__global__ __launch_bounds__(256) void scatter2_kernel(const int* __restrict__ esrc,
                                                       const int* __restrict__ edst,
                                                       int* __restrict__ bcur,
                                                       unsigned int* __restrict__ ebuf) {
    __shared__ int h[NB2];
    __shared__ int cur[NB2];
    for (int i = threadIdx.x; i < NB2; i += 256) h[i] = 0;
    __syncthreads();
    const int base = blockIdx.x * TILE;
    #pragma unroll
    for (int j = 0; j < 16; ++j) {
        int e = base + j * 256 + threadIdx.x;
        if (e < NE) atomicAdd(&h[edst[e] >> 8], 1);
    }
    __syncthreads();
    for (int i = threadIdx.x; i < NB2; i += 256) {
        int c = h[i];
        cur[i] = c ? atomicAdd(&bcur[i], c) : 0;
    }
    __syncthreads();
    #pragma unroll
    for (int j = 0; j < 16; ++j) {
        int e = base + j * 256 + threadIdx.x;
        if (e < NE) {
            int s = esrc[e], d = edst[e];
            int pos = atomicAdd(&cur[d >> 8], 1);
            ebuf[pos] = (unsigned int)s | ((unsigned int)(d & 255) << 24);
        }
    }
}

__global__ __launch_bounds__(256) void csrfill2_kernel(const unsigned int* __restrict__ ebuf,
                                                       const int* __restrict__ bbase,
                                                       int* __restrict__ rp,
                                                       float* __restrict__ dinv,
                                                       int* __restrict__ col) {
    __shared__ int cnt[256];
    __shared__ int cursor[256];
    __shared__ int s[256];
    __shared__ int sbeg, send;
    const int b = blockIdx.x;
    const int t = threadIdx.x;
    if (t == 0) { sbeg = bbase[b]; send = bbase[b + 1]; }
    cnt[t] = 0;
    __syncthreads();
    const int beg = sbeg, end = send;
    const int node0 = b * BKN;

    for (int e = beg + t; e < end; e += 256)
        atomicAdd(&cnt[ebuf[e] >> 24], 1);
    __syncthreads();

    int v = cnt[t];
    s[t] = v;
    __syncthreads();
    for (int off = 1; off < 256; off <<= 1) {
        int a = (t >= off) ? s[t - off] : 0;
        __syncthreads();
        s[t] += a;
        __syncthreads();
    }
    int excl = s[t] - v;
    int gnode = node0 + t;
    if (gnode < NN) {
        rp[gnode]   = beg + excl;
        dinv[gnode] = rsqrtf((float)(v + 1));   // +1 self loop
    }
    cursor[t] = beg + excl;
    if (b == NB2 - 1 && t == 0) rp[NN] = NE;
    __syncthreads();

    for (int e = beg + t; e < end; e += 256) {
        unsigned int sd = ebuf[e];
        int pos = atomicAdd(&cursor[sd >> 24], 1);
        col[pos] = (int)(sd & 0xFFFFFFu);
    }
}

// ---------------- W pre-transpose: Wt[c][k] = bf16(W[k][c]),  c<64 from W0, c>=64 from W1 ----
__global__ __launch_bounds__(256) void wpre_kernel(const float* __restrict__ W0,
                                                   const float* __restrict__ W1,
                                                   int wstride,
                                                   unsigned short* __restrict__ Wt) {
    int e = blockIdx.x * 256 + threadIdx.x;   // grid 64 -> 16384
    int k = e >> 7, c = e & 127;
    float v = (c < 64) ? W0[(size_t)k * wstride + c] : W1[(size_t)k * wstride + (c - 64)];
    Wt[c * 128 + k] = f2bf(v);
}

// ---------------- MFMA GEMM:  H[n][:] = enc( (X[n][:] @ W) * rowScale ) ----------------
// XF32: X fp32 (layer-1 input) vs bf16 spine.  OUT8: fp8 e4m3 output (mid layers) vs bf16.
constexpr int XROW = 136;   // padded shorts per LDS row

template<bool XF32, bool OUT8>
__global__ __launch_bounds__(256) void gemm_mfma_kernel(const void* __restrict__ Xv,
                                                        const unsigned short* __restrict__ Wt,
                                                        const float* __restrict__ dinv,
                                                        int scaleMask,
                                                        void* __restrict__ Ho) {
    __shared__ unsigned short Wl[128 * XROW];   // W^T staged: [col][k]
    __shared__ unsigned short Xl[64 * XROW];    // X tile bf16; reused for output staging

    const int t = threadIdx.x;
    const int rowBase = blockIdx.x * 64;

    // stage Wt -> LDS: 128 rows x 16 chunks (16B)
    #pragma unroll
    for (int i = 0; i < 8; ++i) {
        int f = i * 256 + t;
        int r = f >> 4, c8 = f & 15;
        uint4 w = *(const uint4*)&Wt[r * 128 + c8 * 8];
        *(uint4*)&Wl[r * XROW + c8 * 8] = w;
    }
    // stage X tile -> LDS bf16
    if (XF32) {
        const float* X = (const float*)Xv;
        #pragma unroll
        for (int i = 0; i < 8; ++i) {
            int f = i * 256 + t;                  // 64 rows x 32 float4
            int r = f >> 5, c4 = f & 31;
            int gn = rowBase + r;
            float4 v = make_float4(0.f, 0.f, 0.f, 0.f);
            if (gn < NN) v = *(const float4*)&X[(size_t)gn * 128 + c4 * 4];
            ushort4 o;
            o.x = f2bf(v.x); o.y = f2bf(v.y); o.z = f2bf(v.z); o.w = f2bf(v.w);
            *(ushort4*)&Xl[r * XROW + c4 * 4] = o;
        }
    } else {
        const unsigned short* X = (const unsigned short*)Xv;
        #pragma unroll
        for (int i = 0; i < 4; ++i) {
            int f = i * 256 + t;                  // 64 rows x 16 uint4 chunks
            int r = f >> 4, c8 = f & 15;
            int gn = rowBase + r;
            uint4 v = make_uint4(0u, 0u, 0u, 0u);
            if (gn < NN) v = *(const uint4*)&X[(size_t)gn * 128 + c8 * 8];
            *(uint4*)&Xl[r * XROW + c8 * 8] = v;
        }
    }
    __syncthreads();

    const int w  = t >> 6;        // wave id: rows w*16 .. w*16+15
    const int l  = t & 63;
    const int lr = l & 15;        // A row / B col within 16
    const int lk = (l >> 4) * 8;  // k sub-offset within each 32-k step

    v4f acc[8];
    #pragma unroll
    for (int n = 0; n < 8; ++n) acc[n] = (v4f){0.f, 0.f, 0.f, 0.f};

    const unsigned short* ax = &Xl[(w * 16 + lr) * XROW + lk];
    const unsigned short* bx = &Wl[lr * XROW + lk];

    #pragma unroll
    for (int kk = 0; kk < 4; ++kk) {
        v8bf a = *(const v8bf*)&ax[kk * 32];
        #pragma unroll
        for (int n = 0; n < 8; ++n) {
            v8bf b = *(const v8bf*)&bx[(n * 16) * XROW + kk * 32];
            acc[n] = __builtin_amdgcn_mfma_f32_16x16x32_bf16(a, b, acc[n], 0, 0, 0);
        }
    }

    // epilogue: scale rows, pack bf16 into LDS (D: col=l&15, row=(l>>4)*4+reg)
    #pragma unroll
    for (int r_ = 0; r_ < 4; ++r_) {
        int row  = w * 16 + (l >> 4) * 4 + r_;
        int grow = rowBase + row;
        float dsc = dinv[grow < NN ? grow : NN - 1];
        #pragma unroll
        for (int n = 0; n < 8; ++n) {
            float sc = ((scaleMask >> (n >> 2)) & 1) ? dsc : 1.f;
            Xl[row * XROW + n * 16 + lr] = f2bf(acc[n][r_] * sc);
        }
    }
    __syncthreads();

    // coalesced store: 64 rows x 16 chunks
    if (OUT8) {
        unsigned char* H8 = (unsigned char*)Ho;
        #pragma unroll
        for (int i = 0; i < 4; ++i) {
            int f = i * 256 + t;
            int r = f >> 4, c8 = f & 15;
            int gn = rowBase + r;
            if (gn < NN) {
                uint4 v = *(const uint4*)&Xl[r * XROW + c8 * 8];
                unsigned int lo = __builtin_amdgcn_cvt_pk_fp8_f32(bflo(v.x), bfhi(v.x), 0u, false);
                lo = __builtin_amdgcn_cvt_pk_fp8_f32(bflo(v.y), bfhi(v.y), lo, true);
                unsigned int hi = __builtin_amdgcn_cvt_pk_fp8_f32(bflo(v.z), bfhi(v.z), 0u, false);
                hi = __builtin_amdgcn_cvt_pk_fp8_f32(bflo(v.w), bfhi(v.w), hi, true);
                *(uint2*)&H8[(size_t)gn * 128 + c8 * 8] = make_uint2(lo, hi);
            }
        }
    } else {
        unsigned short* Hb = (unsigned short*)Ho;
        #pragma unroll
        for (int i = 0; i < 4; ++i) {
            int f = i * 256 + t;
            int r = f >> 4, c8 = f & 15;
            int gn = rowBase + r;
            if (gn < NN) {
                uint4 v = *(const uint4*)&Xl[r * XROW + c8 * 8];
                *(uint4*)&Hb[(size_t)gn * 128 + c8 * 8] = v;
            }
        }
    }
}

// ---------------- aggregation: 128-feature layers (conv + bias + residual + relu) ----------------
// H8: fp8 rows (prescaled by dinv[row]). out = relu(dinv[i]*(H[i] + sum_e H[col[e]]) + bias + Xold)
template<bool XF32>
__global__ __launch_bounds__(256) void agg128_kernel(const unsigned char* __restrict__ H8,
                                                     const void* __restrict__ Xoldv,
                                                     const int* __restrict__ rp,
                                                     const int* __restrict__ col,
                                                     const float* __restrict__ dinv,
                                                     const float* __restrict__ bias,
                                                     unsigned int* __restrict__ Xnew) {
    const int wid  = threadIdx.x >> 6;
    const int lane = threadIdx.x & 63;
    const int i = blockIdx.x * 4 + wid;
    if (i >= NN) return;

    const unsigned short* __restrict__ Hs = (const unsigned short*)H8;   // 2 fp8 per ushort

    const float di = dinv[i];
    const float2 b2 = ((const float2*)bias)[lane];
    float xox, xoy;
    if (XF32) {
        float2 xo = ((const float2*)Xoldv)[(size_t)i * 64 + lane];
        xox = xo.x; xoy = xo.y;
    } else {
        unsigned int xo = ((const unsigned int*)Xoldv)[(size_t)i * 64 + lane];
        xox = bflo(xo); xoy = bfhi(xo);
    }

    v2f sf = fp8x2_to_f32(Hs[(size_t)i * 64 + lane]);   // self term
    float ax = sf.x, ay = sf.y;

    const int beg = rp[i], end = rp[i + 1];
    int e = beg;
    for (; e + 8 <= end; e += 8) {
        int s0 = col[e],     s1 = col[e + 1], s2 = col[e + 2], s3 = col[e + 3];
        int s4 = col[e + 4], s5 = col[e + 5], s6 = col[e + 6], s7 = col[e + 7];
        unsigned int u0 = Hs[(size_t)s0 * 64 + lane];
        unsigned int u1 = Hs[(size_t)s1 * 64 + lane];
        unsigned int u2 = Hs[(size_t)s2 * 64 + lane];
        unsigned int u3 = Hs[(size_t)s3 * 64 + lane];
        unsigned int u4 = Hs[(size_t)s4 * 64 + lane];
        unsigned int u5 = Hs[(size_t)s5 * 64 + lane];
        unsigned int u6 = Hs[(size_t)s6 * 64 + lane];
        unsigned int u7 = Hs[(size_t)s7 * 64 + lane];
        v2f m0 = fp8x2_to_f32(u0), m1 = fp8x2_to_f32(u1);
        v2f m2 = fp8x2_to_f32(u2), m3 = fp8x2_to_f32(u3);
        v2f m4 = fp8x2_to_f32(u4), m5 = fp8x2_to_f32(u5);
        v2f m6 = fp8x2_to_f32(u6), m7 = fp8x2_to_f32(u7);
        ax += ((m0.x + m1.x) + (m2.x + m3.x)) + ((m4.x + m5.x) + (m6.x + m7.x));
        ay += ((m0.y + m1.y) + (m2.y + m3.y)) + ((m4.y + m5.y) + (m6.y + m7.y));
    }
    for (; e + 4 <= end; e += 4) {
        int s0 = col[e], s1 = col[e + 1], s2 = col[e + 2], s3 = col[e + 3];
        unsigned int u0 = Hs[(size_t)s0 * 64 + lane];
        unsigned int u1 = Hs[(size_t)s1 * 64 + lane];
        unsigned int u2 = Hs[(size_t)s2 * 64 + lane];
        unsigned int u3 = Hs[(size_t)s3 * 64 + lane];
        v2f m0 = fp8x2_to_f32(u0), m1 = fp8x2_to_f32(u1);
        v2f m2 = fp8x2_to_f32(u2), m3 = fp8x2_to_f32(u3);
        ax += (m0.x + m1.x) + (m2.x + m3.x);
        ay += (m0.y + m1.y) + (m2.y + m3.y);
    }
    for (; e < end; ++e) {
        v2f m = fp8x2_to_f32(Hs[(size_t)col[e] * 64 + lane]);
        ax += m.x;
        ay += m.y;
    }

    float ox = fmaxf(di * ax + b2.x + xox, 0.f);
    float oy = fmaxf(di * ay + b2.y + xoy, 0.f);
    Xnew[(size_t)i * 64 + lane] = pack2bf(ox, oy);
}

// ---------------- final layer: 64-feature conv + bias + skip (bf16 messages) ----------------
__global__ __launch_bounds__(256) void aggout_kernel(const unsigned short* __restrict__ Hb,
                                                     const int* __restrict__ rp,
                                                     const int* __restrict__ col,
                                                     const float* __restrict__ dinv,
                                                     const float* __restrict__ bias,
                                                     float* __restrict__ out) {
    const int wid  = threadIdx.x >> 6;
    const int lane = threadIdx.x & 63;
    const int i = blockIdx.x * 4 + wid;
    if (i >= NN) return;

    const float di = dinv[i];
    const float b  = bias[lane];
    const float sk = bf2f(Hb[(size_t)i * 128 + 64 + lane]);   // skip projection (unscaled)

    float a = bf2f(Hb[(size_t)i * 128 + lane]);               // self term
    const int beg = rp[i], end = rp[i + 1];
    int e = beg;
    for (; e + 8 <= end; e += 8) {
        int s0 = col[e],     s1 = col[e + 1], s2 = col[e + 2], s3 = col[e + 3];
        int s4 = col[e + 4], s5 = col[e + 5], s6 = col[e + 6], s7 = col[e + 7];
        float m0 = bf2f(Hb[(size_t)s0 * 128 + lane]);
        float m1 = bf2f(Hb[(size_t)s1 * 128 + lane]);
        float m2 = bf2f(Hb[(size_t)s2 * 128 + lane]);
        float m3 = bf2f(Hb[(size_t)s3 * 128 + lane]);
        float m4 = bf2f(Hb[(size_t)s4 * 128 + lane]);
        float m5 = bf2f(Hb[(size_t)s5 * 128 + lane]);
        float m6 = bf2f(Hb[(size_t)s6 * 128 + lane]);
        float m7 = bf2f(Hb[(size_t)s7 * 128 + lane]);
        a += ((m0 + m1) + (m2 + m3)) + ((m4 + m5) + (m6 + m7));
    }
    for (; e + 4 <= end; e += 4) {
        int s0 = col[e], s1 = col[e + 1], s2 = col[e + 2], s3 = col[e + 3];
        float m0 = bf2f(Hb[(size_t)s0 * 128 + lane]);
        float m1 = bf2f(Hb[(size_t)s1 * 128 + lane]);
        float m2 = bf2f(Hb[(size_t)s2 * 128 + lane]);
        float m3 = bf2f(Hb[(size_t)s3 * 128 + lane]);
        a += (m0 + m1) + (m2 + m3);
    }
    for (; e < end; ++e) a += bf2f(Hb[(size_t)col[e] * 128 + lane]);

    out[(size_t)i * 64 + lane] = di * a + b + sk;
}

// ---------------- launch ----------------
extern "C" void kernel_launch(void* const* d_in, const int* in_sizes, int n_in,
                              void* d_out, int out_size, void* d_ws, size_t ws_size,
                              hipStream_t stream) {
    const float* x      = (const float*)d_in[0];
    const int*   ei     = (const int*)d_in[1];
    const float* W_in   = (const float*)d_in[2];
    const float* b_in   = (const float*)d_in[3];
    const float* W_mid0 = (const float*)d_in[4];
    const float* b_mid0 = (const float*)d_in[5];
    const float* W_mid1 = (const float*)d_in[6];
    const float* b_mid1 = (const float*)d_in[7];
    const float* W_out  = (const float*)d_in[8];
    const float* b_out  = (const float*)d_in[9];
    const float* W_skip = (const float*)d_in[10];

    const int* esrc = ei;        // edge_index[0]
    const int* edst = ei + NE;   // edge_index[1]

    char* ws = (char*)d_ws;
    int*   bcnt   = (int*)  (ws + OFF_BCNT);
    int*   bbase  = (int*)  (ws + OFF_BBASE);
    int*   bcur   = (int*)  (ws + OFF_BCUR);
    int*   rp     = (int*)  (ws + OFF_RP);
    float* dinv   = (float*)(ws + OFF_DINV);
    int*   col    = (int*)  (ws + OFF_COL);
    unsigned short* wt   = (unsigned short*)(ws + OFF_WT);
    unsigned char*  h8   = (unsigned char*) (ws + OFF_H8);
    unsigned short* hbuf = (unsigned short*)(ws + OFF_H);
    unsigned int*   ebuf = (unsigned int*)  (ws + OFF_H);   // alias: dead before layer-4 GEMM
    unsigned short* xbuf = (unsigned short*)(ws + OFF_X);
    unsigned int*   xbufw = (unsigned int*) (ws + OFF_X);
    float* outp   = (float*)d_out;

    const int gemmGrid = (NN + 63) / 64;             // 1563
    const int aggGrid  = (NN + 3) / 4;               // 25000

    // ---- graph preprocessing ----
    hipMemsetAsync(bcnt, 0, (size_t)(NB2 + 1) * 4, stream);
    bhist_kernel<<<NT, 256, 0, stream>>>(edst, bcnt);
    bscan_kernel<<<1, 512, 0, stream>>>(bcnt, bbase, bcur);
    scatter2_kernel<<<NT, 256, 0, stream>>>(esrc, edst, bcur, ebuf);
    csrfill2_kernel<<<NB2, 256, 0, stream>>>(ebuf, bbase, rp, dinv, col);

    // ---- layer 1 (reads fp32 x; fp8 messages; bf16 spine out) ----
    wpre_kernel<<<64, 256, 0, stream>>>(W_in, W_in + 64, 128, wt);
    gemm_mfma_kernel<true, true><<<gemmGrid, 256, 0, stream>>>(x, wt, dinv, 3, h8);
    agg128_kernel<true><<<aggGrid, 256, 0, stream>>>(h8, x, rp, col, dinv, b_in, xbufw);

    // ---- layer 2 ----
    wpre_kernel<<<64, 256, 0, stream>>>(W_mid0, W_mid0 + 64, 128, wt);
    gemm_mfma_kernel<false, true><<<gemmGrid, 256, 0, stream>>>(xbuf, wt, dinv, 3, h8);
    agg128_kernel<false><<<aggGrid, 256, 0, stream>>>(h8, xbuf, rp, col, dinv, b_mid0, xbufw);

    // ---- layer 3 ----
    wpre_kernel<<<64, 256, 0, stream>>>(W_mid1, W_mid1 + 64, 128, wt);
    gemm_mfma_kernel<false, true><<<gemmGrid, 256, 0, stream>>>(xbuf, wt, dinv, 3, h8);
    agg128_kernel<false><<<aggGrid, 256, 0, stream>>>(h8, xbuf, rp, col, dinv, b_mid1, xbufw);

    // ---- layer 4: fused [W_out | W_skip_out] GEMM (bf16 messages; scale only W_out half) ----
    wpre_kernel<<<64, 256, 0, stream>>>(W_out, W_skip, 64, wt);
    gemm_mfma_kernel<false, false><<<gemmGrid, 256, 0, stream>>>(xbuf, wt, dinv, 1, hbuf);
    aggout_kernel<<<aggGrid, 256, 0, stream>>>(hbuf, rp, col, dinv, b_out, outp);
}